// Round 1
// 1106.741 us; speedup vs baseline: 1.6798x; 1.6798x over previous
//
#include <hip/hip_runtime.h>
#include <math.h>

constexpr int B = 16, S = 1024, D = 256, E = 64, H = 8, HD = 32;

typedef __attribute__((ext_vector_type(8))) short bf16x8;
typedef __attribute__((ext_vector_type(4))) float f32x4;

__device__ __forceinline__ float gelu_f(float x) {
  return 0.5f * x * (1.0f + erff(x * 0.70710678118654752440f));
}

__device__ __forceinline__ unsigned short f2bf(float f) {
  union { float f; unsigned u; } x; x.f = f;
  unsigned r = x.u + 0x7fff + ((x.u >> 16) & 1);
  return (unsigned short)(r >> 16);
}

// async global->LDS, 16B per lane; lds must be wave-uniform-base + lane*16
__device__ __forceinline__ void gl16(const void* g, void* l) {
  __builtin_amdgcn_global_load_lds(
      (const __attribute__((address_space(1))) void*)g,
      (__attribute__((address_space(3))) void*)l, 16, 0, 0);
}

// ---------------- fp32 -> bf16 conversion (weights) ----------------
__global__ void k_cvt(const float* __restrict__ src, unsigned short* __restrict__ dst, int n) {
  int i = (blockIdx.x * 256 + threadIdx.x) * 4;
  if (i >= n) return;
  float4 v = *(const float4*)(src + i);
  dst[i + 0] = f2bf(v.x);
  dst[i + 1] = f2bf(v.y);
  dst[i + 2] = f2bf(v.z);
  dst[i + 3] = f2bf(v.w);
}

// ---------------- embedding: x = tok_emb[tok] + pos_emb[s] (fp32 + bf16) ----------------
__global__ void k_embed(const int* __restrict__ tok,
                        const float* __restrict__ tok_emb,
                        const float* __restrict__ pos_emb,
                        float* __restrict__ x, unsigned short* __restrict__ xb) {
  int bs = blockIdx.x;
  int d = threadIdx.x;
  int s = bs & (S - 1);
  int t = tok[bs];
  float v = tok_emb[(size_t)t * D + d] + pos_emb[s * D + d];
  x[(size_t)bs * D + d] = v;
  xb[(size_t)bs * D + d] = f2bf(v);
}

// ---------------- encoder branch ----------------
__global__ void k_enc(const float* __restrict__ tr, const float* __restrict__ ctx,
                      const float* __restrict__ card,
                      const float* __restrict__ w, const float* __restrict__ bias,
                      const float* __restrict__ g, const float* __restrict__ bt,
                      float* __restrict__ cat) {
  int b = blockIdx.x, i = blockIdx.y, d = threadIdx.x;
  const float* xin = (i == 0 ? tr : (i == 1 ? ctx : card)) + b * E;
  const float* wr = w + ((size_t)i * D + d) * E;
  float acc = bias[i * D + d];
#pragma unroll 8
  for (int e = 0; e < E; ++e) acc += xin[e] * wr[e];
  __shared__ float s1[D], s2[D];
  s1[d] = acc; s2[d] = acc * acc;
  __syncthreads();
  for (int o = D / 2; o > 0; o >>= 1) {
    if (d < o) { s1[d] += s1[d + o]; s2[d] += s2[d + o]; }
    __syncthreads();
  }
  float mean = s1[0] * (1.0f / D);
  float var = s2[0] * (1.0f / D) - mean * mean;
  float nv = (acc - mean) * rsqrtf(var + 1e-5f) * g[i * D + d] + bt[i * D + d];
  cat[(size_t)b * (3 * D) + i * D + d] = gelu_f(nv);
}

// ---------------- fusion ----------------
__global__ void k_fusion(const float* __restrict__ cat, const float* __restrict__ w,
                         const float* __restrict__ bias, const float* __restrict__ g,
                         const float* __restrict__ bt, float* __restrict__ mem) {
  int b = blockIdx.x, d = threadIdx.x;
  const float* xr = cat + (size_t)b * (3 * D);
  const float* wr = w + (size_t)d * (3 * D);
  float acc = bias[d];
  for (int k = 0; k < 3 * D; ++k) acc += xr[k] * wr[k];
  __shared__ float s1[D], s2[D];
  s1[d] = acc; s2[d] = acc * acc;
  __syncthreads();
  for (int o = D / 2; o > 0; o >>= 1) {
    if (d < o) { s1[d] += s1[d + o]; s2[d] += s2[d + o]; }
    __syncthreads();
  }
  float mean = s1[0] * (1.0f / D);
  float var = s2[0] * (1.0f / D) - mean * mean;
  float nv = (acc - mean) * rsqrtf(var + 1e-5f) * g[d] + bt[d];
  mem[(size_t)b * D + d] = gelu_f(nv);
}

// ---------------- cross-attn collapsed ----------------
__global__ void k_ca(const float* __restrict__ mem,
                     const float* __restrict__ in_w, const float* __restrict__ in_b,
                     const float* __restrict__ out_w, const float* __restrict__ out_b,
                     float* __restrict__ ca_add) {
  int b = blockIdx.x, l = blockIdx.y, d = threadIdx.x;
  const float* mr = mem + (size_t)b * D;
  const float* wi = in_w + ((size_t)l * 3 * D + 2 * D + d) * D;
  float v = in_b[(size_t)l * 3 * D + 2 * D + d];
  for (int k = 0; k < D; ++k) v += mr[k] * wi[k];
  __shared__ float vs[D];
  vs[d] = v;
  __syncthreads();
  const float* wo = out_w + ((size_t)l * D + d) * D;
  float o = out_b[(size_t)l * D + d];
  for (int k = 0; k < D; ++k) o += vs[k] * wo[k];
  ca_add[((size_t)l * B + b) * D + d] = o;
}

// ---------------- add + LayerNorm (fp32 out + bf16 shadow) ----------------
__global__ void k_addln(const float* __restrict__ xin, const float* __restrict__ y,
                        int ydiv, float* __restrict__ xout, unsigned short* __restrict__ xb,
                        const float* __restrict__ g, const float* __restrict__ bt) {
  int r = blockIdx.x, d = threadIdx.x;
  float v = xin[(size_t)r * D + d] + y[(size_t)(r / ydiv) * D + d];
  float s1 = v, s2 = v * v;
#pragma unroll
  for (int off = 32; off > 0; off >>= 1) {
    s1 += __shfl_xor(s1, off);
    s2 += __shfl_xor(s2, off);
  }
  __shared__ float w1[4], w2[4];
  int wid = d >> 6, lane = d & 63;
  if (lane == 0) { w1[wid] = s1; w2[wid] = s2; }
  __syncthreads();
  s1 = w1[0] + w1[1] + w1[2] + w1[3];
  s2 = w2[0] + w2[1] + w2[2] + w2[3];
  float mean = s1 * (1.0f / D);
  float var = s2 * (1.0f / D) - mean * mean;
  float o = (v - mean) * rsqrtf(var + 1e-5f) * g[d] + bt[d];
  xout[(size_t)r * D + d] = o;
  xb[(size_t)r * D + d] = f2bf(o);
}

// ---------------- causal flash attention via MFMA (bf16 in, bf16 out) ----------------
// qkv: [B*S][768] bf16, row layout [Q 0..255 | K 256..511 | V 512..767].
// Block: 4 waves x 32 queries = 128 queries for one (b,h). KT=64 keys/step.
// 16x16x32 MFMA: A-frag lane holds M-row (lane&15), k-chunk (lane>>4)*8;
// C layout: col=lane&15, row=(lane>>4)*4+reg (learn_hip m89-verified).
__global__ __launch_bounds__(256)
void k_attn3(const unsigned short* __restrict__ qkv, unsigned short* __restrict__ out) {
  constexpr int KT = 64;
  __shared__ unsigned short Ks[KT * 32];      // [key][32] linear (gl16 dest)
  __shared__ unsigned short Vt[32 * KT];      // [d][key], XOR-swizzled rows
  __shared__ unsigned short Pl[4 * 32 * KT];  // per-wave P [q][k], XOR-swizzled

  const int t = threadIdx.x;
  const int w = t >> 6, lane = t & 63;
  const int lg = lane >> 4, lr = lane & 15;
  const int bh = blockIdx.y;
  const int h = bh & (H - 1), b = bh >> 3;
  const int qtile = (int)gridDim.x - 1 - (int)blockIdx.x;  // biggest tiles first
  const int qb = qtile << 7;
  const int qw = qb + w * 32;  // wave query base
  const unsigned short* base = qkv + (size_t)b * S * 768 + h * HD;

  // Q fragments (A-layout): rows qw + qr*16 + lr, k-chunk lg*8 (HD=32 == MFMA K)
  bf16x8 qf[2];
#pragma unroll
  for (int qr = 0; qr < 2; ++qr)
    qf[qr] = *(const bf16x8*)(base + (size_t)(qw + qr * 16 + lr) * 768 + lg * 8);

  f32x4 o[2][2];  // [qr][dt]
#pragma unroll
  for (int qr = 0; qr < 2; ++qr)
#pragma unroll
    for (int dt = 0; dt < 2; ++dt) o[qr][dt] = (f32x4){0.f, 0.f, 0.f, 0.f};
  float mreg[2][4], lreg[2][4];
#pragma unroll
  for (int qr = 0; qr < 2; ++qr)
#pragma unroll
    for (int r = 0; r < 4; ++r) { mreg[qr][r] = -3.0e38f; lreg[qr][r] = 0.f; }

  const float Cs = 0.17677669529663687f * 1.4426950408889634f;  // 1/sqrt(32) * log2(e)

  // staging: thread t -> key t>>2, 8-elem chunk (t&3)*8
  const int skey = t >> 2;
  const int sch = (t & 3) * 8;
  char* ksdst = (char*)Ks + t * 16;  // wave-uniform base + lane*16

  const int nkt = (qb + 128) >> 6;
  for (int kti = 0; kti < nkt; ++kti) {
    const int kt = kti << 6;
    __syncthreads();  // previous step's LDS reads done
    // K -> LDS, linear [key][32]
    gl16(base + (size_t)(kt + skey) * 768 + 256 + sch, ksdst);
    // V -> regs -> LDS transposed [d][key], swizzle byte ^= (d&7)<<4
    bf16x8 vv = *(const bf16x8*)(base + (size_t)(kt + skey) * 768 + 512 + sch);
#pragma unroll
    for (int j = 0; j < 8; ++j) {
      int d = sch + j;
      int byteo = d * (KT * 2) + ((skey * 2) ^ ((d & 7) << 4));
      *(unsigned short*)((char*)Vt + byteo) = (unsigned short)vv[j];
    }
    __syncthreads();  // tiles resident (drains vmcnt+lgkmcnt)

    if (kt <= qw + 31) {
      // ---- QK^T: 8 MFMAs ----
      bf16x8 kf[4];
#pragma unroll
      for (int t4 = 0; t4 < 4; ++t4)
        kf[t4] = *(const bf16x8*)&Ks[(t4 * 16 + lr) * 32 + lg * 8];
      f32x4 sc[2][4];
#pragma unroll
      for (int qr = 0; qr < 2; ++qr)
#pragma unroll
        for (int t4 = 0; t4 < 4; ++t4)
          sc[qr][t4] = __builtin_amdgcn_mfma_f32_16x16x32_bf16(
              qf[qr], kf[t4], (f32x4){0.f, 0.f, 0.f, 0.f}, 0, 0, 0);

      // ---- causal mask (diagonal tiles only) ----
      if (kt + KT > qw) {
#pragma unroll
        for (int qr = 0; qr < 2; ++qr)
#pragma unroll
          for (int t4 = 0; t4 < 4; ++t4)
#pragma unroll
            for (int r = 0; r < 4; ++r) {
              int q = qw + qr * 16 + lg * 4 + r;
              int k = kt + t4 * 16 + lr;
              if (k > q) sc[qr][t4][r] = -3.0e38f;
            }
      }

      // ---- online softmax, f32, per (qr,r); row spread over 16 lanes ----
      char* pbase = (char*)Pl + (w << 12);
#pragma unroll
      for (int qr = 0; qr < 2; ++qr) {
#pragma unroll
        for (int r = 0; r < 4; ++r) {
          float mx = fmaxf(fmaxf(sc[qr][0][r], sc[qr][1][r]),
                           fmaxf(sc[qr][2][r], sc[qr][3][r]));
#pragma unroll
          for (int msk = 1; msk <= 8; msk <<= 1) mx = fmaxf(mx, __shfl_xor(mx, msk));
          mx = fmaxf(mx, mreg[qr][r]);
          float cf = exp2f((mreg[qr][r] - mx) * Cs);
          mreg[qr][r] = mx;
          float nmxC = -mx * Cs;
          float ps = 0.f;
#pragma unroll
          for (int t4 = 0; t4 < 4; ++t4) {
            float p = exp2f(fmaf(sc[qr][t4][r], Cs, nmxC));
            sc[qr][t4][r] = p;
            ps += p;
          }
#pragma unroll
          for (int msk = 1; msk <= 8; msk <<= 1) ps += __shfl_xor(ps, msk);
          lreg[qr][r] = lreg[qr][r] * cf + ps;
#pragma unroll
          for (int dt = 0; dt < 2; ++dt) o[qr][dt][r] *= cf;
        }
      }

      // ---- P -> wave-local LDS, bf16, [q][k] swizzled ----
#pragma unroll
      for (int qr = 0; qr < 2; ++qr)
#pragma unroll
        for (int t4 = 0; t4 < 4; ++t4)
#pragma unroll
          for (int r = 0; r < 4; ++r) {
            int ql = qr * 16 + lg * 4 + r;
            int k = t4 * 16 + lr;
            int byteo = ql * (KT * 2) + ((k * 2) ^ ((ql & 7) << 4));
            *(unsigned short*)(pbase + byteo) = f2bf(sc[qr][t4][r]);
          }

      // ---- PV: 8 MFMAs over 2 key-passes of 32 ----
#pragma unroll
      for (int kp = 0; kp < 2; ++kp) {
        bf16x8 vf[2], pf[2];
        int kb = kp * 64 + lg * 16;  // byte offset of 16B key-chunk
#pragma unroll
        for (int dt = 0; dt < 2; ++dt) {
          int d = dt * 16 + lr;
          vf[dt] = *(const bf16x8*)((char*)Vt + d * (KT * 2) + (kb ^ ((d & 7) << 4)));
        }
#pragma unroll
        for (int qr = 0; qr < 2; ++qr) {
          int ql = qr * 16 + lr;
          pf[qr] = *(const bf16x8*)(pbase + ql * (KT * 2) + (kb ^ ((ql & 7) << 4)));
        }
#pragma unroll
        for (int qr = 0; qr < 2; ++qr)
#pragma unroll
          for (int dt = 0; dt < 2; ++dt)
            o[qr][dt] = __builtin_amdgcn_mfma_f32_16x16x32_bf16(
                pf[qr], vf[dt], o[qr][dt], 0, 0, 0);
      }
    }
  }

  // ---- epilogue ----
#pragma unroll
  for (int qr = 0; qr < 2; ++qr) {
#pragma unroll
    for (int r = 0; r < 4; ++r) {
      float inv = 1.0f / lreg[qr][r];
      int q = qw + qr * 16 + lg * 4 + r;
      unsigned short* orow = out + (size_t)(b * S + q) * D + h * HD;
#pragma unroll
      for (int dt = 0; dt < 2; ++dt)
        orow[dt * 16 + lr] = f2bf(o[qr][dt][r] * inv);
    }
  }
}

// ---------------- bf16 MFMA GEMM: C[M,N] = A[M,K] @ W[N,K]^T + bias ----------------
// 128x128 tile, BK=32, 4 waves each computing 64x64 via 4x4 frags of 16x16x32.
// EPI: 0=none 1=relu. OUTBF: 0=fp32 out, 1=bf16 out.
template <int EPI, int OUTBF>
__global__ __launch_bounds__(256)
void k_gemm_mfma(const unsigned short* __restrict__ A,
                 const unsigned short* __restrict__ W,
                 const float* __restrict__ bias,
                 void* __restrict__ Cout,
                 int M, int N, int K) {
  __shared__ unsigned short As[128][32];
  __shared__ unsigned short Bs[128][32];
  int t = threadIdx.x;
  int row0 = blockIdx.y * 128, col0 = blockIdx.x * 128;
  int wid = t >> 6, lane = t & 63;
  int wr = wid >> 1, wc = wid & 1;
  int lrow = lane & 15, lko = (lane >> 4) * 8;

  f32x4 acc[4][4];
#pragma unroll
  for (int mi = 0; mi < 4; ++mi)
#pragma unroll
    for (int ni = 0; ni < 4; ++ni)
      acc[mi][ni] = (f32x4){0.f, 0.f, 0.f, 0.f};

  // staging chunks: chunk c in [0,512): row=c>>2, 8-elem quarter q=c&3
  int c0 = t, c1 = t + 256;
  int ar0 = c0 >> 2, aq0 = (c0 & 3) * 8;
  int ar1 = c1 >> 2, aq1 = (c1 & 3) * 8;
  int wrow0 = col0 + ar0; if (wrow0 > N - 1) wrow0 = N - 1;
  int wrow1 = col0 + ar1; if (wrow1 > N - 1) wrow1 = N - 1;

  const unsigned short* A0 = A + (size_t)(row0 + ar0) * K + aq0;
  const unsigned short* A1 = A + (size_t)(row0 + ar1) * K + aq1;
  const unsigned short* W0 = W + (size_t)wrow0 * K + aq0;
  const unsigned short* W1 = W + (size_t)wrow1 * K + aq1;

  for (int kt = 0; kt < K; kt += 32) {
    gl16(A0 + kt, (char*)As + c0 * 16);
    gl16(A1 + kt, (char*)As + c1 * 16);
    gl16(W0 + kt, (char*)Bs + c0 * 16);
    gl16(W1 + kt, (char*)Bs + c1 * 16);
    __syncthreads();  // drains vmcnt -> tiles resident

    bf16x8 af[4], bfr[4];
#pragma unroll
    for (int mi = 0; mi < 4; ++mi)
      af[mi] = *(const bf16x8*)&As[wr * 64 + mi * 16 + lrow][lko];
#pragma unroll
    for (int ni = 0; ni < 4; ++ni)
      bfr[ni] = *(const bf16x8*)&Bs[wc * 64 + ni * 16 + lrow][lko];
#pragma unroll
    for (int mi = 0; mi < 4; ++mi)
#pragma unroll
      for (int ni = 0; ni < 4; ++ni)
        acc[mi][ni] = __builtin_amdgcn_mfma_f32_16x16x32_bf16(af[mi], bfr[ni], acc[mi][ni], 0, 0, 0);
    __syncthreads();  // LDS reads done before next stage
  }

  // epilogue: D row = (lane>>4)*4 + r, col = lane&15  (per 16x16 frag)
  int rbase = row0 + wr * 64 + (lane >> 4) * 4;
  int cbase = col0 + wc * 64 + lrow;
#pragma unroll
  for (int ni = 0; ni < 4; ++ni) {
    int c = cbase + ni * 16;
    if (c < N) {
      float bv = bias[c];
#pragma unroll
      for (int mi = 0; mi < 4; ++mi) {
        int rr = rbase + mi * 16;
#pragma unroll
        for (int r = 0; r < 4; ++r) {
          float v = acc[mi][ni][r] + bv;
          if (EPI == 1) v = fmaxf(v, 0.0f);
          size_t off = (size_t)(rr + r) * N + c;
          if (OUTBF)
            ((unsigned short*)Cout)[off] = f2bf(v);
          else
            ((float*)Cout)[off] = v;
        }
      }
    }
  }
}

extern "C" void kernel_launch(void* const* d_in, const int* in_sizes, int n_in,
                              void* d_out, int out_size, void* d_ws, size_t ws_size,
                              hipStream_t stream) {
  (void)in_sizes; (void)n_in; (void)out_size; (void)ws_size;
  const float* tractovka = (const float*)d_in[0];
  const float* context   = (const float*)d_in[1];
  const float* card      = (const float*)d_in[2];
  const float* enc_w     = (const float*)d_in[3];
  const float* enc_b     = (const float*)d_in[4];
  const float* enc_ln_g  = (const float*)d_in[5];
  const float* enc_ln_b  = (const float*)d_in[6];
  const float* fusion_w  = (const float*)d_in[7];
  const float* fusion_b  = (const float*)d_in[8];
  const float* fusion_ln_g = (const float*)d_in[9];
  const float* fusion_ln_b = (const float*)d_in[10];
  const float* tok_emb   = (const float*)d_in[11];
  const float* pos_emb   = (const float*)d_in[12];
  const float* sa_in_w   = (const float*)d_in[13];
  const float* sa_in_b   = (const float*)d_in[14];
  const float* sa_out_w  = (const float*)d_in[15];
  const float* sa_out_b  = (const float*)d_in[16];
  const float* ca_in_w   = (const float*)d_in[17];
  const float* ca_in_b   = (const float*)d_in[18];
  const float* ca_out_w  = (const float*)d_in[19];
  const float* ca_out_b  = (const float*)d_in[20];
  const float* ln1_g     = (const float*)d_in[21];
  const float* ln1_b     = (const float*)d_in[22];
  const float* ln2_g     = (const float*)d_in[23];
  const float* ln2_b     = (const float*)d_in[24];
  const float* ln3_g     = (const float*)d_in[25];
  const float* ln3_b     = (const float*)d_in[26];
  const float* ffn_w1    = (const float*)d_in[27];
  const float* ffn_b1    = (const float*)d_in[28];
  const float* ffn_w2    = (const float*)d_in[29];
  const float* ffn_b2    = (const float*)d_in[30];
  const float* out_w     = (const float*)d_in[31];
  const float* out_b     = (const float*)d_in[32];
  const int*   prev      = (const int*)d_in[33];
  float* out = (float*)d_out;

  const int M = B * S;  // 16384

  float* ws = (float*)d_ws;
  float* x      = ws;                        // M*D f32
  float* bufA   = x + (size_t)M * D;         // M*768 region (QKV bf16; aliased by ffn1b)
  float* bufB   = bufA + (size_t)M * 768;    // M*D f32
  float* cat    = bufB + (size_t)M * D;      // B*3D
  float* mem    = cat + (size_t)B * 3 * D;   // B*D
  float* ca_add = mem + (size_t)B * D;       // 3*B*D
  unsigned short* xb    = (unsigned short*)(ca_add + (size_t)3 * B * D);  // M*D bf16
  unsigned short* attnb = xb + (size_t)M * D;                             // M*D bf16
  unsigned short* wbf   = attnb + (size_t)M * D;                          // weights bf16
  unsigned short* qkvb  = (unsigned short*)bufA;                          // M*768 bf16 (alias)
  unsigned short* ffn1b = (unsigned short*)bufA;                          // M*1024 bf16 (alias)

  const int n_qkvw = 3 * 768 * D;    // 589824
  const int n_outw = 3 * D * D;      // 196608
  const int n_f1w  = 3 * 1024 * D;   // 786432
  const int n_f2w  = 3 * D * 1024;   // 786432
  const int n_vw   = 10000 * D;      // 2560000
  unsigned short* w_qkv = wbf;
  unsigned short* w_out = w_qkv + n_qkvw;
  unsigned short* w_f1  = w_out + n_outw;
  unsigned short* w_f2  = w_f1 + n_f1w;
  unsigned short* w_v   = w_f2 + n_f2w;

  // weight conversions (fp32 -> bf16), ~20 MB total
  k_cvt<<<(n_qkvw / 4 + 255) / 256, 256, 0, stream>>>(sa_in_w, w_qkv, n_qkvw);
  k_cvt<<<(n_outw / 4 + 255) / 256, 256, 0, stream>>>(sa_out_w, w_out, n_outw);
  k_cvt<<<(n_f1w / 4 + 255) / 256, 256, 0, stream>>>(ffn_w1, w_f1, n_f1w);
  k_cvt<<<(n_f2w / 4 + 255) / 256, 256, 0, stream>>>(ffn_w2, w_f2, n_f2w);
  k_cvt<<<(n_vw / 4 + 255) / 256, 256, 0, stream>>>(out_w, w_v, n_vw);

  // embedding (+bf16 shadow)
  k_embed<<<M, D, 0, stream>>>(prev, tok_emb, pos_emb, x, xb);
  // encoder side path
  k_enc<<<dim3(B, 3), D, 0, stream>>>(tractovka, context, card, enc_w, enc_b,
                                      enc_ln_g, enc_ln_b, cat);
  k_fusion<<<B, D, 0, stream>>>(cat, fusion_w, fusion_b, fusion_ln_g, fusion_ln_b, mem);
  k_ca<<<dim3(B, 3), D, 0, stream>>>(mem, ca_in_w, ca_in_b, ca_out_w, ca_out_b, ca_add);

  for (int l = 0; l < 3; ++l) {
    // QKV: [M,256]@[768,256]^T -> qkvb bf16 [M,768]
    k_gemm_mfma<0, 1><<<dim3(6, M / 128), 256, 0, stream>>>(
        xb, w_qkv + (size_t)l * 768 * D, sa_in_b + (size_t)l * 3 * D, qkvb,
        M, 768, D);
    // causal self-attention (MFMA flash) -> attnb bf16 [M,256]
    k_attn3<<<dim3(S / 128, B * H), 256, 0, stream>>>(qkvb, attnb);
    // out projection -> bufB fp32 [M,256]
    k_gemm_mfma<0, 0><<<dim3(2, M / 128), 256, 0, stream>>>(
        attnb, w_out + (size_t)l * D * D, sa_out_b + (size_t)l * D, bufB,
        M, D, D);
    // x = LN1(x + attn)
    k_addln<<<M, D, 0, stream>>>(x, bufB, 1, x, xb, ln1_g + (size_t)l * D, ln1_b + (size_t)l * D);
    // x = LN2(x + ca_add[l][b])
    k_addln<<<M, D, 0, stream>>>(x, ca_add + (size_t)l * B * D, S, x, xb,
                                 ln2_g + (size_t)l * D, ln2_b + (size_t)l * D);
    // FFN1: relu(x@w1^T+b1) -> ffn1b bf16 [M,1024]
    k_gemm_mfma<1, 1><<<dim3(8, M / 128), 256, 0, stream>>>(
        xb, w_f1 + (size_t)l * 1024 * D, ffn_b1 + (size_t)l * 4 * D, ffn1b,
        M, 1024, D);
    // FFN2: -> bufB fp32 [M,256]
    k_gemm_mfma<0, 0><<<dim3(2, M / 128), 256, 0, stream>>>(
        ffn1b, w_f2 + (size_t)l * D * 1024, ffn_b2 + (size_t)l * D, bufB,
        M, D, 1024);
    // x = LN3(x + ffn)
    k_addln<<<M, D, 0, stream>>>(x, bufB, 1, x, xb, ln3_g + (size_t)l * D, ln3_b + (size_t)l * D);
  }
  // final vocab projection: [M,256]@[10000,256]^T -> out fp32
  k_gemm_mfma<0, 0><<<dim3(79, M / 128), 256, 0, stream>>>(
      xb, w_v, out_b, out, M, 10000, D);
}

// Round 2
// 986.733 us; speedup vs baseline: 1.8841x; 1.1216x over previous
//
#include <hip/hip_runtime.h>
#include <math.h>

constexpr int B = 16, S = 1024, D = 256, E = 64, H = 8, HD = 32;

typedef __attribute__((ext_vector_type(8))) short bf16x8;
typedef __attribute__((ext_vector_type(4))) float f32x4;

__device__ __forceinline__ float gelu_f(float x) {
  return 0.5f * x * (1.0f + erff(x * 0.70710678118654752440f));
}

__device__ __forceinline__ unsigned short f2bf(float f) {
  union { float f; unsigned u; } x; x.f = f;
  unsigned r = x.u + 0x7fff + ((x.u >> 16) & 1);
  return (unsigned short)(r >> 16);
}

// async global->LDS, 16B per lane; lds must be wave-uniform-base + lane*16
__device__ __forceinline__ void gl16(const void* g, void* l) {
  __builtin_amdgcn_global_load_lds(
      (const __attribute__((address_space(1))) void*)g,
      (__attribute__((address_space(3))) void*)l, 16, 0, 0);
}

// ---------------- fp32 -> bf16 conversion (weights) ----------------
__global__ void k_cvt(const float* __restrict__ src, unsigned short* __restrict__ dst, int n) {
  int i = (blockIdx.x * 256 + threadIdx.x) * 4;
  if (i >= n) return;
  float4 v = *(const float4*)(src + i);
  dst[i + 0] = f2bf(v.x);
  dst[i + 1] = f2bf(v.y);
  dst[i + 2] = f2bf(v.z);
  dst[i + 3] = f2bf(v.w);
}

// ---------------- embedding: x = tok_emb[tok] + pos_emb[s] (fp32 + bf16) ----------------
__global__ void k_embed(const int* __restrict__ tok,
                        const float* __restrict__ tok_emb,
                        const float* __restrict__ pos_emb,
                        float* __restrict__ x, unsigned short* __restrict__ xb) {
  int bs = blockIdx.x;
  int d = threadIdx.x;
  int s = bs & (S - 1);
  int t = tok[bs];
  float v = tok_emb[(size_t)t * D + d] + pos_emb[s * D + d];
  x[(size_t)bs * D + d] = v;
  xb[(size_t)bs * D + d] = f2bf(v);
}

// ---------------- encoder branch ----------------
__global__ void k_enc(const float* __restrict__ tr, const float* __restrict__ ctx,
                      const float* __restrict__ card,
                      const float* __restrict__ w, const float* __restrict__ bias,
                      const float* __restrict__ g, const float* __restrict__ bt,
                      float* __restrict__ cat) {
  int b = blockIdx.x, i = blockIdx.y, d = threadIdx.x;
  const float* xin = (i == 0 ? tr : (i == 1 ? ctx : card)) + b * E;
  const float* wr = w + ((size_t)i * D + d) * E;
  float acc = bias[i * D + d];
#pragma unroll 8
  for (int e = 0; e < E; ++e) acc += xin[e] * wr[e];
  __shared__ float s1[D], s2[D];
  s1[d] = acc; s2[d] = acc * acc;
  __syncthreads();
  for (int o = D / 2; o > 0; o >>= 1) {
    if (d < o) { s1[d] += s1[d + o]; s2[d] += s2[d + o]; }
    __syncthreads();
  }
  float mean = s1[0] * (1.0f / D);
  float var = s2[0] * (1.0f / D) - mean * mean;
  float nv = (acc - mean) * rsqrtf(var + 1e-5f) * g[i * D + d] + bt[i * D + d];
  cat[(size_t)b * (3 * D) + i * D + d] = gelu_f(nv);
}

// ---------------- fusion ----------------
__global__ void k_fusion(const float* __restrict__ cat, const float* __restrict__ w,
                         const float* __restrict__ bias, const float* __restrict__ g,
                         const float* __restrict__ bt, float* __restrict__ mem) {
  int b = blockIdx.x, d = threadIdx.x;
  const float* xr = cat + (size_t)b * (3 * D);
  const float* wr = w + (size_t)d * (3 * D);
  float acc = bias[d];
  for (int k = 0; k < 3 * D; ++k) acc += xr[k] * wr[k];
  __shared__ float s1[D], s2[D];
  s1[d] = acc; s2[d] = acc * acc;
  __syncthreads();
  for (int o = D / 2; o > 0; o >>= 1) {
    if (d < o) { s1[d] += s1[d + o]; s2[d] += s2[d + o]; }
    __syncthreads();
  }
  float mean = s1[0] * (1.0f / D);
  float var = s2[0] * (1.0f / D) - mean * mean;
  float nv = (acc - mean) * rsqrtf(var + 1e-5f) * g[d] + bt[d];
  mem[(size_t)b * D + d] = gelu_f(nv);
}

// ---------------- cross-attn collapsed (softmax over 1 key == identity) ----------------
__global__ void k_ca(const float* __restrict__ mem,
                     const float* __restrict__ in_w, const float* __restrict__ in_b,
                     const float* __restrict__ out_w, const float* __restrict__ out_b,
                     float* __restrict__ ca_add) {
  int b = blockIdx.x, l = blockIdx.y, d = threadIdx.x;
  const float* mr = mem + (size_t)b * D;
  const float* wi = in_w + ((size_t)l * 3 * D + 2 * D + d) * D;
  float v = in_b[(size_t)l * 3 * D + 2 * D + d];
  for (int k = 0; k < D; ++k) v += mr[k] * wi[k];
  __shared__ float vs[D];
  vs[d] = v;
  __syncthreads();
  const float* wo = out_w + ((size_t)l * D + d) * D;
  float o = out_b[(size_t)l * D + d];
  for (int k = 0; k < D; ++k) o += vs[k] * wo[k];
  ca_add[((size_t)l * B + b) * D + d] = o;
}

// ---------------- causal flash attention via MFMA (bf16 in, bf16 out) ----------------
// Double-buffered K/V, one barrier per KT step, K/V prefetched one step ahead.
// qkv: [B*S][768] bf16, row layout [Q 0..255 | K 256..511 | V 512..767].
// Block: 4 waves x 32 queries = 128 queries for one (b,h). KT=64 keys/step.
__global__ __launch_bounds__(256)
void k_attn4(const unsigned short* __restrict__ qkv, unsigned short* __restrict__ out) {
  constexpr int KT = 64;
  __shared__ unsigned short Ks[2][KT * 32];   // [key][32] linear (gl16 dest)
  __shared__ unsigned short Vt[2][32 * KT];   // [d][key], XOR-swizzled rows
  __shared__ unsigned short Pl[4 * 32 * KT];  // per-wave P [q][k], XOR-swizzled

  const int t = threadIdx.x;
  const int w = t >> 6, lane = t & 63;
  const int lg = lane >> 4, lr = lane & 15;
  const int bh = blockIdx.y;
  const int h = bh & (H - 1), b = bh >> 3;
  const int qtile = (int)gridDim.x - 1 - (int)blockIdx.x;  // biggest tiles first
  const int qb = qtile << 7;
  const int qw = qb + w * 32;  // wave query base
  const unsigned short* base = qkv + (size_t)b * S * 768 + h * HD;

  // Q fragments (A-layout): rows qw + qr*16 + lr, k-chunk lg*8 (HD=32 == MFMA K)
  bf16x8 qf[2];
#pragma unroll
  for (int qr = 0; qr < 2; ++qr)
    qf[qr] = *(const bf16x8*)(base + (size_t)(qw + qr * 16 + lr) * 768 + lg * 8);

  f32x4 o[2][2];  // [qr][dt]
#pragma unroll
  for (int qr = 0; qr < 2; ++qr)
#pragma unroll
    for (int dt = 0; dt < 2; ++dt) o[qr][dt] = (f32x4){0.f, 0.f, 0.f, 0.f};
  float mreg[2][4], lreg[2][4];  // lreg is LANE-LOCAL partial (reduced in epilogue)
#pragma unroll
  for (int qr = 0; qr < 2; ++qr)
#pragma unroll
    for (int r = 0; r < 4; ++r) { mreg[qr][r] = -3.0e38f; lreg[qr][r] = 0.f; }

  const float Cs = 0.17677669529663687f * 1.4426950408889634f;  // 1/sqrt(32)*log2(e)

  // staging: thread t -> key t>>2, 8-elem chunk (t&3)*8
  const int skey = t >> 2;
  const int sch = (t & 3) * 8;
  char* pbase = (char*)Pl + (w << 12);

  const int nkt = (qb + 128) >> 6;  // >= 2 always

  // prologue: stage step 0
  gl16(base + (size_t)skey * 768 + 256 + sch, (char*)Ks[0] + t * 16);
  bf16x8 vv = *(const bf16x8*)(base + (size_t)skey * 768 + 512 + sch);
  __syncthreads();  // K0 resident (vmcnt drained), vv loaded

  for (int kti = 0; kti < nkt; ++kti) {
    const int kt = kti << 6;
    const int cur = kti & 1;

    // write current V tile (regs -> LDS transposed, swizzle byte ^= (d&7)<<4)
#pragma unroll
    for (int j = 0; j < 8; ++j) {
      int d = sch + j;
      int byteo = d * (KT * 2) + ((skey * 2) ^ ((d & 7) << 4));
      *(unsigned short*)((char*)Vt[cur] + byteo) = (unsigned short)vv[j];
    }
    // prefetch next step's K (gl16) and V (regs) — latency hides under QK^T+softmax
    if (kti + 1 < nkt) {
      const unsigned short* nb = base + (size_t)(kt + KT + skey) * 768;
      gl16(nb + 256 + sch, (char*)Ks[cur ^ 1] + t * 16);
      vv = *(const bf16x8*)(nb + 512 + sch);
    }

    const bool active = (kt <= qw + 31);
    if (active) {
      // ---- QK^T: 8 MFMAs (Ks[cur] resident since previous barrier) ----
      bf16x8 kf[4];
#pragma unroll
      for (int t4 = 0; t4 < 4; ++t4)
        kf[t4] = *(const bf16x8*)&Ks[cur][(t4 * 16 + lr) * 32 + lg * 8];
      f32x4 sc[2][4];
#pragma unroll
      for (int qr = 0; qr < 2; ++qr)
#pragma unroll
        for (int t4 = 0; t4 < 4; ++t4)
          sc[qr][t4] = __builtin_amdgcn_mfma_f32_16x16x32_bf16(
              qf[qr], kf[t4], (f32x4){0.f, 0.f, 0.f, 0.f}, 0, 0, 0);

      // ---- causal mask (diagonal tiles only) ----
      if (kt + KT > qw) {
#pragma unroll
        for (int qr = 0; qr < 2; ++qr)
#pragma unroll
          for (int t4 = 0; t4 < 4; ++t4)
#pragma unroll
            for (int r = 0; r < 4; ++r) {
              int q = qw + qr * 16 + lg * 4 + r;
              int k = kt + t4 * 16 + lr;
              if (k > q) sc[qr][t4][r] = -3.0e38f;
            }
      }

      // ---- online softmax: max-reduce only; l kept lane-local ----
#pragma unroll
      for (int qr = 0; qr < 2; ++qr) {
#pragma unroll
        for (int r = 0; r < 4; ++r) {
          float mx = fmaxf(fmaxf(sc[qr][0][r], sc[qr][1][r]),
                           fmaxf(sc[qr][2][r], sc[qr][3][r]));
#pragma unroll
          for (int msk = 1; msk <= 8; msk <<= 1) mx = fmaxf(mx, __shfl_xor(mx, msk));
          mx = fmaxf(mx, mreg[qr][r]);
          float cf = exp2f((mreg[qr][r] - mx) * Cs);
          mreg[qr][r] = mx;
          float nmxC = -mx * Cs;
          float ps = 0.f;
#pragma unroll
          for (int t4 = 0; t4 < 4; ++t4) {
            float p = exp2f(fmaf(sc[qr][t4][r], Cs, nmxC));
            sc[qr][t4][r] = p;
            ps += p;
          }
          lreg[qr][r] = lreg[qr][r] * cf + ps;
#pragma unroll
          for (int dt = 0; dt < 2; ++dt) o[qr][dt][r] *= cf;
        }
      }

      // ---- P -> wave-local LDS, bf16, [q][k] swizzled ----
#pragma unroll
      for (int qr = 0; qr < 2; ++qr)
#pragma unroll
        for (int t4 = 0; t4 < 4; ++t4)
#pragma unroll
          for (int r = 0; r < 4; ++r) {
            int ql = qr * 16 + lg * 4 + r;
            int k = t4 * 16 + lr;
            int byteo = ql * (KT * 2) + ((k * 2) ^ ((ql & 7) << 4));
            *(unsigned short*)(pbase + byteo) = f2bf(sc[qr][t4][r]);
          }
    }

    // single barrier: Vt[cur]+P writes visible; next K gl16 drained; vv loaded
    __syncthreads();

    if (active) {
      // ---- PV: 8 MFMAs over 2 key-passes of 32 ----
#pragma unroll
      for (int kp = 0; kp < 2; ++kp) {
        bf16x8 vf[2], pf[2];
        int kb = kp * 64 + lg * 16;  // byte offset of 16B key-chunk
#pragma unroll
        for (int dt = 0; dt < 2; ++dt) {
          int d = dt * 16 + lr;
          vf[dt] = *(const bf16x8*)((char*)Vt[cur] + d * (KT * 2) + (kb ^ ((d & 7) << 4)));
        }
#pragma unroll
        for (int qr = 0; qr < 2; ++qr) {
          int ql = qr * 16 + lr;
          pf[qr] = *(const bf16x8*)(pbase + ql * (KT * 2) + (kb ^ ((ql & 7) << 4)));
        }
#pragma unroll
        for (int qr = 0; qr < 2; ++qr)
#pragma unroll
          for (int dt = 0; dt < 2; ++dt)
            o[qr][dt] = __builtin_amdgcn_mfma_f32_16x16x32_bf16(
                pf[qr], vf[dt], o[qr][dt], 0, 0, 0);
      }
    }
  }

  // ---- epilogue: reduce lane-local l across the 16-lane row group ----
#pragma unroll
  for (int qr = 0; qr < 2; ++qr) {
#pragma unroll
    for (int r = 0; r < 4; ++r) {
      float ls = lreg[qr][r];
#pragma unroll
      for (int msk = 1; msk <= 8; msk <<= 1) ls += __shfl_xor(ls, msk);
      float inv = 1.0f / ls;
      int q = qw + qr * 16 + lg * 4 + r;
      unsigned short* orow = out + (size_t)(b * S + q) * D + h * HD;
#pragma unroll
      for (int dt = 0; dt < 2; ++dt)
        orow[dt * 16 + lr] = f2bf(o[qr][dt][r] * inv);
    }
  }
}

// ---------------- bf16 MFMA GEMM: C[M,N] = A[M,K] @ W[N,K]^T + bias ----------------
// 128x128 tile, BK=32, 4 waves each computing 64x64 via 4x4 frags of 16x16x32.
// EPI: 0=none 1=relu. OUTBF: 0=fp32 out, 1=bf16 out.
template <int EPI, int OUTBF>
__global__ __launch_bounds__(256)
void k_gemm_mfma(const unsigned short* __restrict__ A,
                 const unsigned short* __restrict__ W,
                 const float* __restrict__ bias,
                 void* __restrict__ Cout,
                 int M, int N, int K) {
  __shared__ unsigned short As[128][32];
  __shared__ unsigned short Bs[128][32];
  int t = threadIdx.x;
  int row0 = blockIdx.y * 128, col0 = blockIdx.x * 128;
  int wid = t >> 6, lane = t & 63;
  int wr = wid >> 1, wc = wid & 1;
  int lrow = lane & 15, lko = (lane >> 4) * 8;

  f32x4 acc[4][4];
#pragma unroll
  for (int mi = 0; mi < 4; ++mi)
#pragma unroll
    for (int ni = 0; ni < 4; ++ni)
      acc[mi][ni] = (f32x4){0.f, 0.f, 0.f, 0.f};

  int c0 = t, c1 = t + 256;
  int ar0 = c0 >> 2, aq0 = (c0 & 3) * 8;
  int ar1 = c1 >> 2, aq1 = (c1 & 3) * 8;
  int wrow0 = col0 + ar0; if (wrow0 > N - 1) wrow0 = N - 1;
  int wrow1 = col0 + ar1; if (wrow1 > N - 1) wrow1 = N - 1;

  const unsigned short* A0 = A + (size_t)(row0 + ar0) * K + aq0;
  const unsigned short* A1 = A + (size_t)(row0 + ar1) * K + aq1;
  const unsigned short* W0 = W + (size_t)wrow0 * K + aq0;
  const unsigned short* W1 = W + (size_t)wrow1 * K + aq1;

  for (int kt = 0; kt < K; kt += 32) {
    gl16(A0 + kt, (char*)As + c0 * 16);
    gl16(A1 + kt, (char*)As + c1 * 16);
    gl16(W0 + kt, (char*)Bs + c0 * 16);
    gl16(W1 + kt, (char*)Bs + c1 * 16);
    __syncthreads();

    bf16x8 af[4], bfr[4];
#pragma unroll
    for (int mi = 0; mi < 4; ++mi)
      af[mi] = *(const bf16x8*)&As[wr * 64 + mi * 16 + lrow][lko];
#pragma unroll
    for (int ni = 0; ni < 4; ++ni)
      bfr[ni] = *(const bf16x8*)&Bs[wc * 64 + ni * 16 + lrow][lko];
#pragma unroll
    for (int mi = 0; mi < 4; ++mi)
#pragma unroll
      for (int ni = 0; ni < 4; ++ni)
        acc[mi][ni] = __builtin_amdgcn_mfma_f32_16x16x32_bf16(af[mi], bfr[ni], acc[mi][ni], 0, 0, 0);
    __syncthreads();
  }

  int rbase = row0 + wr * 64 + (lane >> 4) * 4;
  int cbase = col0 + wc * 64 + lrow;
#pragma unroll
  for (int ni = 0; ni < 4; ++ni) {
    int c = cbase + ni * 16;
    if (c < N) {
      float bv = bias[c];
#pragma unroll
      for (int mi = 0; mi < 4; ++mi) {
        int rr = rbase + mi * 16;
#pragma unroll
        for (int r = 0; r < 4; ++r) {
          float v = acc[mi][ni][r] + bv;
          if (EPI == 1) v = fmaxf(v, 0.0f);
          size_t off = (size_t)(rr + r) * N + c;
          if (OUTBF)
            ((unsigned short*)Cout)[off] = f2bf(v);
          else
            ((float*)Cout)[off] = v;
        }
      }
    }
  }
}

// ---------------- fused GEMM (N=256) + residual + 1 or 2 LayerNorms ----------------
// Tile 64 rows x 256 cols (full row), 4 waves (one per 64-col chunk), BK=32.
// NLN==1: x = LN(res + A@W^T + bias; g1,b1)
// NLN==2: x1 = LN1(res + A@W^T + bias); x = LN2(x1 + ca[row/S]; g2,b2)
// Writes x fp32 and bf16 shadow xb.
template <int NLN>
__global__ __launch_bounds__(256)
void k_gemm_ln(const unsigned short* __restrict__ A,
               const unsigned short* __restrict__ W,
               const float* __restrict__ bias,
               const float* __restrict__ res,
               const float* __restrict__ ca,
               const float* __restrict__ g1, const float* __restrict__ b1,
               const float* __restrict__ g2, const float* __restrict__ b2,
               float* __restrict__ xout, unsigned short* __restrict__ xb,
               int K) {
  __shared__ unsigned short As[64][32];
  __shared__ unsigned short Bs[256][32];
  __shared__ float red[2][64][4];
  int t = threadIdx.x;
  int row0 = blockIdx.x * 64;
  int wc = t >> 6, lane = t & 63;
  int lr = lane & 15, lg = lane >> 4;

  f32x4 acc[4][4];  // [mi rows][ni cols]
#pragma unroll
  for (int mi = 0; mi < 4; ++mi)
#pragma unroll
    for (int ni = 0; ni < 4; ++ni)
      acc[mi][ni] = (f32x4){0.f, 0.f, 0.f, 0.f};

  // staging: 1280 16B-chunks (As 256 + Bs 1024), 5 per thread
  const unsigned short* srcs[5];
  char* dsts[5];
#pragma unroll
  for (int i = 0; i < 5; ++i) {
    int c = t + (i << 8);
    if (c < 256) {
      int rw = c >> 2, q = (c & 3) * 8;
      srcs[i] = A + (size_t)(row0 + rw) * K + q;
      dsts[i] = (char*)As + c * 16;
    } else {
      int cb = c - 256;
      int rw = cb >> 2, q = (cb & 3) * 8;
      srcs[i] = W + (size_t)rw * K + q;
      dsts[i] = (char*)Bs + cb * 16;
    }
  }

  for (int kt = 0; kt < K; kt += 32) {
#pragma unroll
    for (int i = 0; i < 5; ++i) gl16(srcs[i] + kt, dsts[i]);
    __syncthreads();
    bf16x8 af[4], bfr[4];
#pragma unroll
    for (int mi = 0; mi < 4; ++mi)
      af[mi] = *(const bf16x8*)&As[mi * 16 + lr][lg * 8];
#pragma unroll
    for (int ni = 0; ni < 4; ++ni)
      bfr[ni] = *(const bf16x8*)&Bs[wc * 64 + ni * 16 + lr][lg * 8];
#pragma unroll
    for (int mi = 0; mi < 4; ++mi)
#pragma unroll
      for (int ni = 0; ni < 4; ++ni)
        acc[mi][ni] = __builtin_amdgcn_mfma_f32_16x16x32_bf16(af[mi], bfr[ni], acc[mi][ni], 0, 0, 0);
    __syncthreads();
  }

  // ---- epilogue: v = acc + bias + res; LN over the full 256-col row ----
  int colb = wc * 64 + lr;
  float mean[4][4], rstd[4][4];

  // pass 1: accumulate + wave-partial row sums
#pragma unroll
  for (int mi = 0; mi < 4; ++mi) {
#pragma unroll
    for (int r = 0; r < 4; ++r) {
      int rowl = mi * 16 + lg * 4 + r;
      int rowg = row0 + rowl;
      float s1 = 0.f, s2 = 0.f;
#pragma unroll
      for (int ni = 0; ni < 4; ++ni) {
        int c = colb + ni * 16;
        float v = acc[mi][ni][r] + bias[c] + res[(size_t)rowg * D + c];
        acc[mi][ni][r] = v;
        s1 += v; s2 += v * v;
      }
#pragma unroll
      for (int msk = 1; msk <= 8; msk <<= 1) {
        s1 += __shfl_xor(s1, msk);
        s2 += __shfl_xor(s2, msk);
      }
      if (lr == 0) { red[0][rowl][wc] = s1; red[1][rowl][wc] = s2; }
    }
  }
  __syncthreads();
#pragma unroll
  for (int mi = 0; mi < 4; ++mi)
#pragma unroll
    for (int r = 0; r < 4; ++r) {
      int rowl = mi * 16 + lg * 4 + r;
      f32x4 a = *(const f32x4*)&red[0][rowl][0];
      f32x4 bq = *(const f32x4*)&red[1][rowl][0];
      float s1 = a[0] + a[1] + a[2] + a[3];
      float s2 = bq[0] + bq[1] + bq[2] + bq[3];
      float mn = s1 * (1.0f / D);
      float vr = s2 * (1.0f / D) - mn * mn;
      mean[mi][r] = mn;
      rstd[mi][r] = rsqrtf(vr + 1e-5f);
    }
  // apply LN1
#pragma unroll
  for (int mi = 0; mi < 4; ++mi)
#pragma unroll
    for (int ni = 0; ni < 4; ++ni) {
      int c = colb + ni * 16;
      float gg = g1[c], bb = b1[c];
#pragma unroll
      for (int r = 0; r < 4; ++r)
        acc[mi][ni][r] = (acc[mi][ni][r] - mean[mi][r]) * rstd[mi][r] * gg + bb;
    }

  if (NLN == 2) {
    __syncthreads();  // red reads done; safe to rewrite
#pragma unroll
    for (int mi = 0; mi < 4; ++mi) {
#pragma unroll
      for (int r = 0; r < 4; ++r) {
        int rowl = mi * 16 + lg * 4 + r;
        int rowg = row0 + rowl;
        int bidx = rowg >> 10;  // row / S
        float s1 = 0.f, s2 = 0.f;
#pragma unroll
        for (int ni = 0; ni < 4; ++ni) {
          int c = colb + ni * 16;
          float v = acc[mi][ni][r] + ca[(size_t)bidx * D + c];
          acc[mi][ni][r] = v;
          s1 += v; s2 += v * v;
        }
#pragma unroll
        for (int msk = 1; msk <= 8; msk <<= 1) {
          s1 += __shfl_xor(s1, msk);
          s2 += __shfl_xor(s2, msk);
        }
        if (lr == 0) { red[0][rowl][wc] = s1; red[1][rowl][wc] = s2; }
      }
    }
    __syncthreads();
#pragma unroll
    for (int mi = 0; mi < 4; ++mi)
#pragma unroll
      for (int r = 0; r < 4; ++r) {
        int rowl = mi * 16 + lg * 4 + r;
        f32x4 a = *(const f32x4*)&red[0][rowl][0];
        f32x4 bq = *(const f32x4*)&red[1][rowl][0];
        float s1 = a[0] + a[1] + a[2] + a[3];
        float s2 = bq[0] + bq[1] + bq[2] + bq[3];
        float mn = s1 * (1.0f / D);
        float vr = s2 * (1.0f / D) - mn * mn;
        mean[mi][r] = mn;
        rstd[mi][r] = rsqrtf(vr + 1e-5f);
      }
#pragma unroll
    for (int mi = 0; mi < 4; ++mi)
#pragma unroll
      for (int ni = 0; ni < 4; ++ni) {
        int c = colb + ni * 16;
        float gg = g2[c], bb = b2[c];
#pragma unroll
        for (int r = 0; r < 4; ++r)
          acc[mi][ni][r] = (acc[mi][ni][r] - mean[mi][r]) * rstd[mi][r] * gg + bb;
      }
  }

  // write x fp32 + bf16 shadow
#pragma unroll
  for (int mi = 0; mi < 4; ++mi)
#pragma unroll
    for (int r = 0; r < 4; ++r) {
      int rowg = row0 + mi * 16 + lg * 4 + r;
#pragma unroll
      for (int ni = 0; ni < 4; ++ni) {
        int c = colb + ni * 16;
        float v = acc[mi][ni][r];
        xout[(size_t)rowg * D + c] = v;
        xb[(size_t)rowg * D + c] = f2bf(v);
      }
    }
}

extern "C" void kernel_launch(void* const* d_in, const int* in_sizes, int n_in,
                              void* d_out, int out_size, void* d_ws, size_t ws_size,
                              hipStream_t stream) {
  (void)in_sizes; (void)n_in; (void)out_size; (void)ws_size;
  const float* tractovka = (const float*)d_in[0];
  const float* context   = (const float*)d_in[1];
  const float* card      = (const float*)d_in[2];
  const float* enc_w     = (const float*)d_in[3];
  const float* enc_b     = (const float*)d_in[4];
  const float* enc_ln_g  = (const float*)d_in[5];
  const float* enc_ln_b  = (const float*)d_in[6];
  const float* fusion_w  = (const float*)d_in[7];
  const float* fusion_b  = (const float*)d_in[8];
  const float* fusion_ln_g = (const float*)d_in[9];
  const float* fusion_ln_b = (const float*)d_in[10];
  const float* tok_emb   = (const float*)d_in[11];
  const float* pos_emb   = (const float*)d_in[12];
  const float* sa_in_w   = (const float*)d_in[13];
  const float* sa_in_b   = (const float*)d_in[14];
  const float* sa_out_w  = (const float*)d_in[15];
  const float* sa_out_b  = (const float*)d_in[16];
  const float* ca_in_w   = (const float*)d_in[17];
  const float* ca_in_b   = (const float*)d_in[18];
  const float* ca_out_w  = (const float*)d_in[19];
  const float* ca_out_b  = (const float*)d_in[20];
  const float* ln1_g     = (const float*)d_in[21];
  const float* ln1_b     = (const float*)d_in[22];
  const float* ln2_g     = (const float*)d_in[23];
  const float* ln2_b     = (const float*)d_in[24];
  const float* ln3_g     = (const float*)d_in[25];
  const float* ln3_b     = (const float*)d_in[26];
  const float* ffn_w1    = (const float*)d_in[27];
  const float* ffn_b1    = (const float*)d_in[28];
  const float* ffn_w2    = (const float*)d_in[29];
  const float* ffn_b2    = (const float*)d_in[30];
  const float* out_w     = (const float*)d_in[31];
  const float* out_b     = (const float*)d_in[32];
  const int*   prev      = (const int*)d_in[33];
  float* out = (float*)d_out;

  const int M = B * S;  // 16384

  float* ws = (float*)d_ws;
  float* x      = ws;                        // M*D f32
  float* bufA   = x + (size_t)M * D;         // M*768 region (QKV bf16; aliased by ffn1b)
  float* bufB   = bufA + (size_t)M * 768;    // M*D f32 (unused now, kept for layout)
  float* cat    = bufB + (size_t)M * D;      // B*3D
  float* mem    = cat + (size_t)B * 3 * D;   // B*D
  float* ca_add = mem + (size_t)B * D;       // 3*B*D
  unsigned short* xb    = (unsigned short*)(ca_add + (size_t)3 * B * D);  // M*D bf16
  unsigned short* attnb = xb + (size_t)M * D;                             // M*D bf16
  unsigned short* wbf   = attnb + (size_t)M * D;                          // weights bf16
  unsigned short* qkvb  = (unsigned short*)bufA;                          // M*768 bf16 (alias)
  unsigned short* ffn1b = (unsigned short*)bufA;                          // M*1024 bf16 (alias)

  const int n_qkvw = 3 * 768 * D;    // 589824
  const int n_outw = 3 * D * D;      // 196608
  const int n_f1w  = 3 * 1024 * D;   // 786432
  const int n_f2w  = 3 * D * 1024;   // 786432
  const int n_vw   = 10000 * D;      // 2560000
  unsigned short* w_qkv = wbf;
  unsigned short* w_out = w_qkv + n_qkvw;
  unsigned short* w_f1  = w_out + n_outw;
  unsigned short* w_f2  = w_f1 + n_f1w;
  unsigned short* w_v   = w_f2 + n_f2w;

  // weight conversions (fp32 -> bf16), ~20 MB total
  k_cvt<<<(n_qkvw / 4 + 255) / 256, 256, 0, stream>>>(sa_in_w, w_qkv, n_qkvw);
  k_cvt<<<(n_outw / 4 + 255) / 256, 256, 0, stream>>>(sa_out_w, w_out, n_outw);
  k_cvt<<<(n_f1w / 4 + 255) / 256, 256, 0, stream>>>(ffn_w1, w_f1, n_f1w);
  k_cvt<<<(n_f2w / 4 + 255) / 256, 256, 0, stream>>>(ffn_w2, w_f2, n_f2w);
  k_cvt<<<(n_vw / 4 + 255) / 256, 256, 0, stream>>>(out_w, w_v, n_vw);

  // embedding (+bf16 shadow)
  k_embed<<<M, D, 0, stream>>>(prev, tok_emb, pos_emb, x, xb);
  // encoder side path
  k_enc<<<dim3(B, 3), D, 0, stream>>>(tractovka, context, card, enc_w, enc_b,
                                      enc_ln_g, enc_ln_b, cat);
  k_fusion<<<B, D, 0, stream>>>(cat, fusion_w, fusion_b, fusion_ln_g, fusion_ln_b, mem);
  k_ca<<<dim3(B, 3), D, 0, stream>>>(mem, ca_in_w, ca_in_b, ca_out_w, ca_out_b, ca_add);

  for (int l = 0; l < 3; ++l) {
    // QKV: [M,256]@[768,256]^T -> qkvb bf16 [M,768]
    k_gemm_mfma<0, 1><<<dim3(6, M / 128), 256, 0, stream>>>(
        xb, w_qkv + (size_t)l * 768 * D, sa_in_b + (size_t)l * 3 * D, qkvb,
        M, 768, D);
    // causal self-attention (MFMA flash, pipelined) -> attnb bf16 [M,256]
    k_attn4<<<dim3(S / 128, B * H), 256, 0, stream>>>(qkvb, attnb);
    // out-proj + LN1 + (+ca_add) + LN2 fused -> x fp32, xb bf16
    k_gemm_ln<2><<<dim3(M / 64), 256, 0, stream>>>(
        attnb, w_out + (size_t)l * D * D, sa_out_b + (size_t)l * D,
        x, ca_add + (size_t)l * B * D,
        ln1_g + (size_t)l * D, ln1_b + (size_t)l * D,
        ln2_g + (size_t)l * D, ln2_b + (size_t)l * D,
        x, xb, D);
    // FFN1: relu(x@w1^T+b1) -> ffn1b bf16 [M,1024]
    k_gemm_mfma<1, 1><<<dim3(8, M / 128), 256, 0, stream>>>(
        xb, w_f1 + (size_t)l * 1024 * D, ffn_b1 + (size_t)l * 4 * D, ffn1b,
        M, 1024, D);
    // FFN2 + LN3 fused -> x fp32, xb bf16
    k_gemm_ln<1><<<dim3(M / 64), 256, 0, stream>>>(
        ffn1b, w_f2 + (size_t)l * D * 1024, ffn_b2 + (size_t)l * D,
        x, nullptr,
        ln3_g + (size_t)l * D, ln3_b + (size_t)l * D,
        nullptr, nullptr,
        x, xb, 1024);
  }
  // final vocab projection: [M,256]@[10000,256]^T -> out fp32
  k_gemm_mfma<0, 0><<<dim3(79, M / 128), 256, 0, stream>>>(
      xb, w_v, out_b, out, M, 10000, D);
}

// Round 3
// 877.402 us; speedup vs baseline: 2.1189x; 1.1246x over previous
//
#include <hip/hip_runtime.h>
#include <math.h>

constexpr int B = 16, S = 1024, D = 256, E = 64, H = 8, HD = 32;

typedef __attribute__((ext_vector_type(8))) short bf16x8;
typedef __attribute__((ext_vector_type(4))) float f32x4;

__device__ __forceinline__ float gelu_f(float x) {
  return 0.5f * x * (1.0f + erff(x * 0.70710678118654752440f));
}

__device__ __forceinline__ unsigned short f2bf(float f) {
  union { float f; unsigned u; } x; x.f = f;
  unsigned r = x.u + 0x7fff + ((x.u >> 16) & 1);
  return (unsigned short)(r >> 16);
}

// packed f32x2 -> bf16x2 (RNE), low half = a, high half = b
__device__ __forceinline__ unsigned cvt_pk_bf16(float a, float b) {
  unsigned r;
  asm("v_cvt_pk_bf16_f32 %0, %1, %2" : "=v"(r) : "v"(a), "v"(b));
  return r;
}

// async global->LDS, 16B per lane; lds must be wave-uniform-base + lane*16
__device__ __forceinline__ void gl16(const void* g, void* l) {
  __builtin_amdgcn_global_load_lds(
      (const __attribute__((address_space(1))) void*)g,
      (__attribute__((address_space(3))) void*)l, 16, 0, 0);
}

// ---------------- fp32 -> bf16 conversion (weights) ----------------
__global__ void k_cvt(const float* __restrict__ src, unsigned short* __restrict__ dst, int n) {
  int i = (blockIdx.x * 256 + threadIdx.x) * 4;
  if (i >= n) return;
  float4 v = *(const float4*)(src + i);
  dst[i + 0] = f2bf(v.x);
  dst[i + 1] = f2bf(v.y);
  dst[i + 2] = f2bf(v.z);
  dst[i + 3] = f2bf(v.w);
}

// ---------------- embedding: x = tok_emb[tok] + pos_emb[s] (fp32 + bf16) ----------------
__global__ void k_embed(const int* __restrict__ tok,
                        const float* __restrict__ tok_emb,
                        const float* __restrict__ pos_emb,
                        float* __restrict__ x, unsigned short* __restrict__ xb) {
  int bs = blockIdx.x;
  int d = threadIdx.x;
  int s = bs & (S - 1);
  int t = tok[bs];
  float v = tok_emb[(size_t)t * D + d] + pos_emb[s * D + d];
  x[(size_t)bs * D + d] = v;
  xb[(size_t)bs * D + d] = f2bf(v);
}

// ---------------- encoder branch ----------------
__global__ void k_enc(const float* __restrict__ tr, const float* __restrict__ ctx,
                      const float* __restrict__ card,
                      const float* __restrict__ w, const float* __restrict__ bias,
                      const float* __restrict__ g, const float* __restrict__ bt,
                      float* __restrict__ cat) {
  int b = blockIdx.x, i = blockIdx.y, d = threadIdx.x;
  const float* xin = (i == 0 ? tr : (i == 1 ? ctx : card)) + b * E;
  const float* wr = w + ((size_t)i * D + d) * E;
  float acc = bias[i * D + d];
#pragma unroll 8
  for (int e = 0; e < E; ++e) acc += xin[e] * wr[e];
  __shared__ float s1[D], s2[D];
  s1[d] = acc; s2[d] = acc * acc;
  __syncthreads();
  for (int o = D / 2; o > 0; o >>= 1) {
    if (d < o) { s1[d] += s1[d + o]; s2[d] += s2[d + o]; }
    __syncthreads();
  }
  float mean = s1[0] * (1.0f / D);
  float var = s2[0] * (1.0f / D) - mean * mean;
  float nv = (acc - mean) * rsqrtf(var + 1e-5f) * g[i * D + d] + bt[i * D + d];
  cat[(size_t)b * (3 * D) + i * D + d] = gelu_f(nv);
}

// ---------------- fusion ----------------
__global__ void k_fusion(const float* __restrict__ cat, const float* __restrict__ w,
                         const float* __restrict__ bias, const float* __restrict__ g,
                         const float* __restrict__ bt, float* __restrict__ mem) {
  int b = blockIdx.x, d = threadIdx.x;
  const float* xr = cat + (size_t)b * (3 * D);
  const float* wr = w + (size_t)d * (3 * D);
  float acc = bias[d];
  for (int k = 0; k < 3 * D; ++k) acc += xr[k] * wr[k];
  __shared__ float s1[D], s2[D];
  s1[d] = acc; s2[d] = acc * acc;
  __syncthreads();
  for (int o = D / 2; o > 0; o >>= 1) {
    if (d < o) { s1[d] += s1[d + o]; s2[d] += s2[d + o]; }
    __syncthreads();
  }
  float mean = s1[0] * (1.0f / D);
  float var = s2[0] * (1.0f / D) - mean * mean;
  float nv = (acc - mean) * rsqrtf(var + 1e-5f) * g[d] + bt[d];
  mem[(size_t)b * D + d] = gelu_f(nv);
}

// ---------------- cross-attn collapsed (softmax over 1 key == identity) ----------------
__global__ void k_ca(const float* __restrict__ mem,
                     const float* __restrict__ in_w, const float* __restrict__ in_b,
                     const float* __restrict__ out_w, const float* __restrict__ out_b,
                     float* __restrict__ ca_add) {
  int b = blockIdx.x, l = blockIdx.y, d = threadIdx.x;
  const float* mr = mem + (size_t)b * D;
  const float* wi = in_w + ((size_t)l * 3 * D + 2 * D + d) * D;
  float v = in_b[(size_t)l * 3 * D + 2 * D + d];
  for (int k = 0; k < D; ++k) v += mr[k] * wi[k];
  __shared__ float vs[D];
  vs[d] = v;
  __syncthreads();
  const float* wo = out_w + ((size_t)l * D + d) * D;
  float o = out_b[(size_t)l * D + d];
  for (int k = 0; k < D; ++k) o += vs[k] * wo[k];
  ca_add[((size_t)l * B + b) * D + d] = o;
}

// ---------------- causal flash attention via MFMA, swapped-QK^T softmax ----------------
// qkv: [B*S][768] bf16, row layout [Q 0..255 | K 256..511 | V 512..767].
// Block: 4 waves x 32 queries = 128 queries for one (b,h). KT=64 keys/step.
// QK^T computed as mfma(K,Q): C col=lane&15 = q, row=(lane>>4)*4+reg = k.
// -> each lane holds 16 P-values of ONE query row (its lg-group's k subset):
//    row max = 15 lane-local fmax + 2 shfl_xor(16,32); row sum lane-local.
// PV unchanged: P round-trips LDS [q][k] (XOR swizzle), read back as A-frag.
__global__ __launch_bounds__(256)
void k_attn5(const unsigned short* __restrict__ qkv, unsigned short* __restrict__ out) {
  constexpr int KT = 64;
  __shared__ unsigned short Ks[2][KT * 32];   // [key][32] linear (gl16 dest)
  __shared__ unsigned short Vt[2][32 * KT];   // [d][key], XOR-swizzled rows
  __shared__ unsigned short Pl[4 * 32 * KT];  // per-wave P [q][k], XOR-swizzled

  const int t = threadIdx.x;
  const int w = t >> 6, lane = t & 63;
  const int lg = lane >> 4, lr = lane & 15;
  const int bh = blockIdx.y;
  const int h = bh & (H - 1), b = bh >> 3;
  const int qtile = (int)gridDim.x - 1 - (int)blockIdx.x;  // biggest tiles first
  const int qb = qtile << 7;
  const int qw = qb + w * 32;  // wave query base
  const unsigned short* base = qkv + (size_t)b * S * 768 + h * HD;

  // Q fragments (B-frag for swapped QK^T; same layout as A-frag):
  // lane holds q-row qw + qr*16 + lr, k-chunk lg*8
  bf16x8 qf[2];
#pragma unroll
  for (int qr = 0; qr < 2; ++qr)
    qf[qr] = *(const bf16x8*)(base + (size_t)(qw + qr * 16 + lr) * 768 + lg * 8);

  f32x4 o[2][2];  // [qr][dt]; C-layout: col d = dt*16+lr, row q = qr*16+lg*4+r
#pragma unroll
  for (int qr = 0; qr < 2; ++qr)
#pragma unroll
    for (int dt = 0; dt < 2; ++dt) o[qr][dt] = (f32x4){0.f, 0.f, 0.f, 0.f};
  float mq[2], lq[2];  // running max / LANE-LOCAL partial sum for q = qw+qr*16+lr
#pragma unroll
  for (int qr = 0; qr < 2; ++qr) { mq[qr] = -3.0e38f; lq[qr] = 0.f; }

  const float Cs = 0.17677669529663687f * 1.4426950408889634f;  // 1/sqrt(32)*log2(e)

  // staging: thread t -> key t>>2, 8-elem chunk (t&3)*8
  const int skey = t >> 2;
  const int sch = (t & 3) * 8;
  char* pbase = (char*)Pl + (w << 12);

  const int nkt = (qb + 128) >> 6;  // >= 2 always

  // prologue: stage step 0
  gl16(base + (size_t)skey * 768 + 256 + sch, (char*)Ks[0] + t * 16);
  bf16x8 vv = *(const bf16x8*)(base + (size_t)skey * 768 + 512 + sch);
  __syncthreads();  // K0 resident (vmcnt drained), vv loaded

  for (int kti = 0; kti < nkt; ++kti) {
    const int kt = kti << 6;
    const int cur = kti & 1;

    // write current V tile (regs -> LDS transposed, swizzle byte ^= (d&7)<<4)
#pragma unroll
    for (int j = 0; j < 8; ++j) {
      int d = sch + j;
      int byteo = d * (KT * 2) + ((skey * 2) ^ ((d & 7) << 4));
      *(unsigned short*)((char*)Vt[cur] + byteo) = (unsigned short)vv[j];
    }
    // prefetch next step's K (gl16) and V (regs) — latency hides under QK^T+softmax
    if (kti + 1 < nkt) {
      const unsigned short* nb = base + (size_t)(kt + KT + skey) * 768;
      gl16(nb + 256 + sch, (char*)Ks[cur ^ 1] + t * 16);
      vv = *(const bf16x8*)(nb + 512 + sch);
    }

    const bool active = (kt <= qw + 31);
    if (active) {
      // ---- QK^T (swapped): sc[qr][t4] = mfma(K-tile, Q-tile) ----
      bf16x8 kf[4];
#pragma unroll
      for (int t4 = 0; t4 < 4; ++t4)
        kf[t4] = *(const bf16x8*)&Ks[cur][(t4 * 16 + lr) * 32 + lg * 8];
      f32x4 sc[2][4];
      __builtin_amdgcn_s_setprio(1);
#pragma unroll
      for (int qr = 0; qr < 2; ++qr)
#pragma unroll
        for (int t4 = 0; t4 < 4; ++t4)
          sc[qr][t4] = __builtin_amdgcn_mfma_f32_16x16x32_bf16(
              kf[t4], qf[qr], (f32x4){0.f, 0.f, 0.f, 0.f}, 0, 0, 0);
      __builtin_amdgcn_s_setprio(0);

      // ---- causal mask (diagonal tiles only): k = kt+t4*16+lg*4+r, q = qw+qr*16+lr
      if (kt + KT > qw) {
#pragma unroll
        for (int qr = 0; qr < 2; ++qr) {
          int q = qw + qr * 16 + lr;
#pragma unroll
          for (int t4 = 0; t4 < 4; ++t4)
#pragma unroll
            for (int r = 0; r < 4; ++r) {
              int k = kt + t4 * 16 + lg * 4 + r;
              if (k > q) sc[qr][t4][r] = -3.0e38f;
            }
        }
      }

      // ---- online softmax: per-q state lives at lane lr == q&15, all lg copies ----
#pragma unroll
      for (int qr = 0; qr < 2; ++qr) {
        // lane-local max over this lane's 16 k-values
        float mx = sc[qr][0][0];
#pragma unroll
        for (int t4 = 0; t4 < 4; ++t4)
#pragma unroll
          for (int r = 0; r < 4; ++r) mx = fmaxf(mx, sc[qr][t4][r]);
        // combine the 4 lg-groups (full 64-k row max)
        mx = fmaxf(mx, __shfl_xor(mx, 16));
        mx = fmaxf(mx, __shfl_xor(mx, 32));
        mx = fmaxf(mx, mq[qr]);
        float cf = exp2f((mq[qr] - mx) * Cs);
        mq[qr] = mx;
        float nmxC = -mx * Cs;
        float ps = 0.f;
#pragma unroll
        for (int t4 = 0; t4 < 4; ++t4)
#pragma unroll
          for (int r = 0; r < 4; ++r) {
            float p = exp2f(fmaf(sc[qr][t4][r], Cs, nmxC));
            sc[qr][t4][r] = p;
            ps += p;
          }
        lq[qr] = lq[qr] * cf + ps;  // lane-local partial (this lg's k subset)
        // broadcast cf into the o C-layout row mapping (row = lg*4+r) and rescale
#pragma unroll
        for (int r = 0; r < 4; ++r) {
          float cfo = __shfl(cf, (lane & 48) | (lg * 4 + r));
          o[qr][0][r] *= cfo;
          o[qr][1][r] *= cfo;
        }
        // ---- P -> wave-local LDS: per t4, 4 contiguous k -> 1 ds_write_b64 ----
        int ql = qr * 16 + lr;
        int swz = (ql & 7) << 4;
        char* prow = pbase + ql * (KT * 2);
#pragma unroll
        for (int t4 = 0; t4 < 4; ++t4) {
          unsigned lo = cvt_pk_bf16(sc[qr][t4][0], sc[qr][t4][1]);
          unsigned hi = cvt_pk_bf16(sc[qr][t4][2], sc[qr][t4][3]);
          *(uint2*)(prow + ((t4 * 32 + lg * 8) ^ swz)) = make_uint2(lo, hi);
        }
      }
    }

    // single barrier: Vt[cur]+P writes visible; next K gl16 drained; vv loaded
    __syncthreads();

    if (active) {
      // ---- PV: 8 MFMAs over 2 key-passes of 32 ----
#pragma unroll
      for (int kp = 0; kp < 2; ++kp) {
        bf16x8 vf[2], pf[2];
        int kb = kp * 64 + lg * 16;  // byte offset of 16B key-chunk
#pragma unroll
        for (int dt = 0; dt < 2; ++dt) {
          int d = dt * 16 + lr;
          vf[dt] = *(const bf16x8*)((char*)Vt[cur] + d * (KT * 2) + (kb ^ ((d & 7) << 4)));
        }
#pragma unroll
        for (int qr = 0; qr < 2; ++qr) {
          int ql = qr * 16 + lr;
          pf[qr] = *(const bf16x8*)(pbase + ql * (KT * 2) + (kb ^ ((ql & 7) << 4)));
        }
        __builtin_amdgcn_s_setprio(1);
#pragma unroll
        for (int qr = 0; qr < 2; ++qr)
#pragma unroll
          for (int dt = 0; dt < 2; ++dt)
            o[qr][dt] = __builtin_amdgcn_mfma_f32_16x16x32_bf16(
                pf[qr], vf[dt], o[qr][dt], 0, 0, 0);
        __builtin_amdgcn_s_setprio(0);
      }
    }
  }

  // ---- epilogue: total l per q (reduce lg-groups), broadcast to o-layout ----
#pragma unroll
  for (int qr = 0; qr < 2; ++qr) {
    float ls = lq[qr];
    ls += __shfl_xor(ls, 16);
    ls += __shfl_xor(ls, 32);
    float invq = 1.0f / ls;  // for q = qw + qr*16 + lr
#pragma unroll
    for (int r = 0; r < 4; ++r) {
      float inv = __shfl(invq, (lane & 48) | (lg * 4 + r));
      int q = qw + qr * 16 + lg * 4 + r;
      unsigned short* orow = out + (size_t)(b * S + q) * D + h * HD;
#pragma unroll
      for (int dt = 0; dt < 2; ++dt)
        orow[dt * 16 + lr] = f2bf(o[qr][dt][r] * inv);
    }
  }
}

// ---------------- bf16 MFMA GEMM: C[M,N] = A[M,K] @ W[N,K]^T + bias ----------------
// 128x128 tile, BK=32, 4 waves each computing 64x64 via 4x4 frags of 16x16x32.
// EPI: 0=none 1=relu. OUTBF: 0=fp32 out, 1=bf16 out.
template <int EPI, int OUTBF>
__global__ __launch_bounds__(256)
void k_gemm_mfma(const unsigned short* __restrict__ A,
                 const unsigned short* __restrict__ W,
                 const float* __restrict__ bias,
                 void* __restrict__ Cout,
                 int M, int N, int K) {
  __shared__ unsigned short As[128][32];
  __shared__ unsigned short Bs[128][32];
  int t = threadIdx.x;
  int row0 = blockIdx.y * 128, col0 = blockIdx.x * 128;
  int wid = t >> 6, lane = t & 63;
  int wr = wid >> 1, wc = wid & 1;
  int lrow = lane & 15, lko = (lane >> 4) * 8;

  f32x4 acc[4][4];
#pragma unroll
  for (int mi = 0; mi < 4; ++mi)
#pragma unroll
    for (int ni = 0; ni < 4; ++ni)
      acc[mi][ni] = (f32x4){0.f, 0.f, 0.f, 0.f};

  int c0 = t, c1 = t + 256;
  int ar0 = c0 >> 2, aq0 = (c0 & 3) * 8;
  int ar1 = c1 >> 2, aq1 = (c1 & 3) * 8;
  int wrow0 = col0 + ar0; if (wrow0 > N - 1) wrow0 = N - 1;
  int wrow1 = col0 + ar1; if (wrow1 > N - 1) wrow1 = N - 1;

  const unsigned short* A0 = A + (size_t)(row0 + ar0) * K + aq0;
  const unsigned short* A1 = A + (size_t)(row0 + ar1) * K + aq1;
  const unsigned short* W0 = W + (size_t)wrow0 * K + aq0;
  const unsigned short* W1 = W + (size_t)wrow1 * K + aq1;

  for (int kt = 0; kt < K; kt += 32) {
    gl16(A0 + kt, (char*)As + c0 * 16);
    gl16(A1 + kt, (char*)As + c1 * 16);
    gl16(W0 + kt, (char*)Bs + c0 * 16);
    gl16(W1 + kt, (char*)Bs + c1 * 16);
    __syncthreads();

    bf16x8 af[4], bfr[4];
#pragma unroll
    for (int mi = 0; mi < 4; ++mi)
      af[mi] = *(const bf16x8*)&As[wr * 64 + mi * 16 + lrow][lko];
#pragma unroll
    for (int ni = 0; ni < 4; ++ni)
      bfr[ni] = *(const bf16x8*)&Bs[wc * 64 + ni * 16 + lrow][lko];
#pragma unroll
    for (int mi = 0; mi < 4; ++mi)
#pragma unroll
      for (int ni = 0; ni < 4; ++ni)
        acc[mi][ni] = __builtin_amdgcn_mfma_f32_16x16x32_bf16(af[mi], bfr[ni], acc[mi][ni], 0, 0, 0);
    __syncthreads();
  }

  int rbase = row0 + wr * 64 + (lane >> 4) * 4;
  int cbase = col0 + wc * 64 + lrow;
#pragma unroll
  for (int ni = 0; ni < 4; ++ni) {
    int c = cbase + ni * 16;
    if (c < N) {
      float bv = bias[c];
#pragma unroll
      for (int mi = 0; mi < 4; ++mi) {
        int rr = rbase + mi * 16;
#pragma unroll
        for (int r = 0; r < 4; ++r) {
          float v = acc[mi][ni][r] + bv;
          if (EPI == 1) v = fmaxf(v, 0.0f);
          size_t off = (size_t)(rr + r) * N + c;
          if (OUTBF)
            ((unsigned short*)Cout)[off] = f2bf(v);
          else
            ((float*)Cout)[off] = v;
        }
      }
    }
  }
}

// ---------------- fused GEMM (N=256) + residual + 1 or 2 LayerNorms ----------------
// Tile 64 rows x 256 cols (full row), 4 waves (one per 64-col chunk), BK=32.
// NLN==1: x = LN(res + A@W^T + bias; g1,b1)
// NLN==2: x1 = LN1(res + A@W^T + bias); x = LN2(x1 + ca[row/S]; g2,b2)
// Writes x fp32 and bf16 shadow xb.
template <int NLN>
__global__ __launch_bounds__(256)
void k_gemm_ln(const unsigned short* __restrict__ A,
               const unsigned short* __restrict__ W,
               const float* __restrict__ bias,
               const float* __restrict__ res,
               const float* __restrict__ ca,
               const float* __restrict__ g1, const float* __restrict__ b1,
               const float* __restrict__ g2, const float* __restrict__ b2,
               float* __restrict__ xout, unsigned short* __restrict__ xb,
               int K) {
  __shared__ unsigned short As[64][32];
  __shared__ unsigned short Bs[256][32];
  __shared__ float red[2][64][4];
  int t = threadIdx.x;
  int row0 = blockIdx.x * 64;
  int wc = t >> 6, lane = t & 63;
  int lr = lane & 15, lg = lane >> 4;

  f32x4 acc[4][4];  // [mi rows][ni cols]
#pragma unroll
  for (int mi = 0; mi < 4; ++mi)
#pragma unroll
    for (int ni = 0; ni < 4; ++ni)
      acc[mi][ni] = (f32x4){0.f, 0.f, 0.f, 0.f};

  // staging: 1280 16B-chunks (As 256 + Bs 1024), 5 per thread
  const unsigned short* srcs[5];
  char* dsts[5];
#pragma unroll
  for (int i = 0; i < 5; ++i) {
    int c = t + (i << 8);
    if (c < 256) {
      int rw = c >> 2, q = (c & 3) * 8;
      srcs[i] = A + (size_t)(row0 + rw) * K + q;
      dsts[i] = (char*)As + c * 16;
    } else {
      int cb = c - 256;
      int rw = cb >> 2, q = (cb & 3) * 8;
      srcs[i] = W + (size_t)rw * K + q;
      dsts[i] = (char*)Bs + cb * 16;
    }
  }

  for (int kt = 0; kt < K; kt += 32) {
#pragma unroll
    for (int i = 0; i < 5; ++i) gl16(srcs[i] + kt, dsts[i]);
    __syncthreads();
    bf16x8 af[4], bfr[4];
#pragma unroll
    for (int mi = 0; mi < 4; ++mi)
      af[mi] = *(const bf16x8*)&As[mi * 16 + lr][lg * 8];
#pragma unroll
    for (int ni = 0; ni < 4; ++ni)
      bfr[ni] = *(const bf16x8*)&Bs[wc * 64 + ni * 16 + lr][lg * 8];
#pragma unroll
    for (int mi = 0; mi < 4; ++mi)
#pragma unroll
      for (int ni = 0; ni < 4; ++ni)
        acc[mi][ni] = __builtin_amdgcn_mfma_f32_16x16x32_bf16(af[mi], bfr[ni], acc[mi][ni], 0, 0, 0);
    __syncthreads();
  }

  // ---- epilogue: v = acc + bias + res; LN over the full 256-col row ----
  int colb = wc * 64 + lr;
  float mean[4][4], rstd[4][4];

  // pass 1: accumulate + wave-partial row sums
#pragma unroll
  for (int mi = 0; mi < 4; ++mi) {
#pragma unroll
    for (int r = 0; r < 4; ++r) {
      int rowl = mi * 16 + lg * 4 + r;
      int rowg = row0 + rowl;
      float s1 = 0.f, s2 = 0.f;
#pragma unroll
      for (int ni = 0; ni < 4; ++ni) {
        int c = colb + ni * 16;
        float v = acc[mi][ni][r] + bias[c] + res[(size_t)rowg * D + c];
        acc[mi][ni][r] = v;
        s1 += v; s2 += v * v;
      }
#pragma unroll
      for (int msk = 1; msk <= 8; msk <<= 1) {
        s1 += __shfl_xor(s1, msk);
        s2 += __shfl_xor(s2, msk);
      }
      if (lr == 0) { red[0][rowl][wc] = s1; red[1][rowl][wc] = s2; }
    }
  }
  __syncthreads();
#pragma unroll
  for (int mi = 0; mi < 4; ++mi)
#pragma unroll
    for (int r = 0; r < 4; ++r) {
      int rowl = mi * 16 + lg * 4 + r;
      f32x4 a = *(const f32x4*)&red[0][rowl][0];
      f32x4 bq = *(const f32x4*)&red[1][rowl][0];
      float s1 = a[0] + a[1] + a[2] + a[3];
      float s2 = bq[0] + bq[1] + bq[2] + bq[3];
      float mn = s1 * (1.0f / D);
      float vr = s2 * (1.0f / D) - mn * mn;
      mean[mi][r] = mn;
      rstd[mi][r] = rsqrtf(vr + 1e-5f);
    }
  // apply LN1
#pragma unroll
  for (int mi = 0; mi < 4; ++mi)
#pragma unroll
    for (int ni = 0; ni < 4; ++ni) {
      int c = colb + ni * 16;
      float gg = g1[c], bb = b1[c];
#pragma unroll
      for (int r = 0; r < 4; ++r)
        acc[mi][ni][r] = (acc[mi][ni][r] - mean[mi][r]) * rstd[mi][r] * gg + bb;
    }

  if (NLN == 2) {
    __syncthreads();  // red reads done; safe to rewrite
#pragma unroll
    for (int mi = 0; mi < 4; ++mi) {
#pragma unroll
      for (int r = 0; r < 4; ++r) {
        int rowl = mi * 16 + lg * 4 + r;
        int rowg = row0 + rowl;
        int bidx = rowg >> 10;  // row / S
        float s1 = 0.f, s2 = 0.f;
#pragma unroll
        for (int ni = 0; ni < 4; ++ni) {
          int c = colb + ni * 16;
          float v = acc[mi][ni][r] + ca[(size_t)bidx * D + c];
          acc[mi][ni][r] = v;
          s1 += v; s2 += v * v;
        }
#pragma unroll
        for (int msk = 1; msk <= 8; msk <<= 1) {
          s1 += __shfl_xor(s1, msk);
          s2 += __shfl_xor(s2, msk);
        }
        if (lr == 0) { red[0][rowl][wc] = s1; red[1][rowl][wc] = s2; }
      }
    }
    __syncthreads();
#pragma unroll
    for (int mi = 0; mi < 4; ++mi)
#pragma unroll
      for (int r = 0; r < 4; ++r) {
        int rowl = mi * 16 + lg * 4 + r;
        f32x4 a = *(const f32x4*)&red[0][rowl][0];
        f32x4 bq = *(const f32x4*)&red[1][rowl][0];
        float s1 = a[0] + a[1] + a[2] + a[3];
        float s2 = bq[0] + bq[1] + bq[2] + bq[3];
        float mn = s1 * (1.0f / D);
        float vr = s2 * (1.0f / D) - mn * mn;
        mean[mi][r] = mn;
        rstd[mi][r] = rsqrtf(vr + 1e-5f);
      }
#pragma unroll
    for (int mi = 0; mi < 4; ++mi)
#pragma unroll
      for (int ni = 0; ni < 4; ++ni) {
        int c = colb + ni * 16;
        float gg = g2[c], bb = b2[c];
#pragma unroll
        for (int r = 0; r < 4; ++r)
          acc[mi][ni][r] = (acc[mi][ni][r] - mean[mi][r]) * rstd[mi][r] * gg + bb;
      }
  }

  // write x fp32 + bf16 shadow
#pragma unroll
  for (int mi = 0; mi < 4; ++mi)
#pragma unroll
    for (int r = 0; r < 4; ++r) {
      int rowg = row0 + mi * 16 + lg * 4 + r;
#pragma unroll
      for (int ni = 0; ni < 4; ++ni) {
        int c = colb + ni * 16;
        float v = acc[mi][ni][r];
        xout[(size_t)rowg * D + c] = v;
        xb[(size_t)rowg * D + c] = f2bf(v);
      }
    }
}

extern "C" void kernel_launch(void* const* d_in, const int* in_sizes, int n_in,
                              void* d_out, int out_size, void* d_ws, size_t ws_size,
                              hipStream_t stream) {
  (void)in_sizes; (void)n_in; (void)out_size; (void)ws_size;
  const float* tractovka = (const float*)d_in[0];
  const float* context   = (const float*)d_in[1];
  const float* card      = (const float*)d_in[2];
  const float* enc_w     = (const float*)d_in[3];
  const float* enc_b     = (const float*)d_in[4];
  const float* enc_ln_g  = (const float*)d_in[5];
  const float* enc_ln_b  = (const float*)d_in[6];
  const float* fusion_w  = (const float*)d_in[7];
  const float* fusion_b  = (const float*)d_in[8];
  const float* fusion_ln_g = (const float*)d_in[9];
  const float* fusion_ln_b = (const float*)d_in[10];
  const float* tok_emb   = (const float*)d_in[11];
  const float* pos_emb   = (const float*)d_in[12];
  const float* sa_in_w   = (const float*)d_in[13];
  const float* sa_in_b   = (const float*)d_in[14];
  const float* sa_out_w  = (const float*)d_in[15];
  const float* sa_out_b  = (const float*)d_in[16];
  const float* ca_in_w   = (const float*)d_in[17];
  const float* ca_in_b   = (const float*)d_in[18];
  const float* ca_out_w  = (const float*)d_in[19];
  const float* ca_out_b  = (const float*)d_in[20];
  const float* ln1_g     = (const float*)d_in[21];
  const float* ln1_b     = (const float*)d_in[22];
  const float* ln2_g     = (const float*)d_in[23];
  const float* ln2_b     = (const float*)d_in[24];
  const float* ln3_g     = (const float*)d_in[25];
  const float* ln3_b     = (const float*)d_in[26];
  const float* ffn_w1    = (const float*)d_in[27];
  const float* ffn_b1    = (const float*)d_in[28];
  const float* ffn_w2    = (const float*)d_in[29];
  const float* ffn_b2    = (const float*)d_in[30];
  const float* out_w     = (const float*)d_in[31];
  const float* out_b     = (const float*)d_in[32];
  const int*   prev      = (const int*)d_in[33];
  float* out = (float*)d_out;

  const int M = B * S;  // 16384

  float* ws = (float*)d_ws;
  float* x      = ws;                        // M*D f32
  float* bufA   = x + (size_t)M * D;         // M*768 region (QKV bf16; aliased by ffn1b)
  float* bufB   = bufA + (size_t)M * 768;    // M*D f32 (unused now, kept for layout)
  float* cat    = bufB + (size_t)M * D;      // B*3D
  float* mem    = cat + (size_t)B * 3 * D;   // B*D
  float* ca_add = mem + (size_t)B * D;       // 3*B*D
  unsigned short* xb    = (unsigned short*)(ca_add + (size_t)3 * B * D);  // M*D bf16
  unsigned short* attnb = xb + (size_t)M * D;                             // M*D bf16
  unsigned short* wbf   = attnb + (size_t)M * D;                          // weights bf16
  unsigned short* qkvb  = (unsigned short*)bufA;                          // M*768 bf16 (alias)
  unsigned short* ffn1b = (unsigned short*)bufA;                          // M*1024 bf16 (alias)

  const int n_qkvw = 3 * 768 * D;    // 589824
  const int n_outw = 3 * D * D;      // 196608
  const int n_f1w  = 3 * 1024 * D;   // 786432
  const int n_f2w  = 3 * D * 1024;   // 786432
  const int n_vw   = 10000 * D;      // 2560000
  unsigned short* w_qkv = wbf;
  unsigned short* w_out = w_qkv + n_qkvw;
  unsigned short* w_f1  = w_out + n_outw;
  unsigned short* w_f2  = w_f1 + n_f1w;
  unsigned short* w_v   = w_f2 + n_f2w;

  // weight conversions (fp32 -> bf16), ~20 MB total
  k_cvt<<<(n_qkvw / 4 + 255) / 256, 256, 0, stream>>>(sa_in_w, w_qkv, n_qkvw);
  k_cvt<<<(n_outw / 4 + 255) / 256, 256, 0, stream>>>(sa_out_w, w_out, n_outw);
  k_cvt<<<(n_f1w / 4 + 255) / 256, 256, 0, stream>>>(ffn_w1, w_f1, n_f1w);
  k_cvt<<<(n_f2w / 4 + 255) / 256, 256, 0, stream>>>(ffn_w2, w_f2, n_f2w);
  k_cvt<<<(n_vw / 4 + 255) / 256, 256, 0, stream>>>(out_w, w_v, n_vw);

  // embedding (+bf16 shadow)
  k_embed<<<M, D, 0, stream>>>(prev, tok_emb, pos_emb, x, xb);
  // encoder side path
  k_enc<<<dim3(B, 3), D, 0, stream>>>(tractovka, context, card, enc_w, enc_b,
                                      enc_ln_g, enc_ln_b, cat);
  k_fusion<<<B, D, 0, stream>>>(cat, fusion_w, fusion_b, fusion_ln_g, fusion_ln_b, mem);
  k_ca<<<dim3(B, 3), D, 0, stream>>>(mem, ca_in_w, ca_in_b, ca_out_w, ca_out_b, ca_add);

  for (int l = 0; l < 3; ++l) {
    // QKV: [M,256]@[768,256]^T -> qkvb bf16 [M,768]
    k_gemm_mfma<0, 1><<<dim3(6, M / 128), 256, 0, stream>>>(
        xb, w_qkv + (size_t)l * 768 * D, sa_in_b + (size_t)l * 3 * D, qkvb,
        M, 768, D);
    // causal self-attention (MFMA flash, swapped softmax) -> attnb bf16 [M,256]
    k_attn5<<<dim3(S / 128, B * H), 256, 0, stream>>>(qkvb, attnb);
    // out-proj + LN1 + (+ca_add) + LN2 fused -> x fp32, xb bf16
    k_gemm_ln<2><<<dim3(M / 64), 256, 0, stream>>>(
        attnb, w_out + (size_t)l * D * D, sa_out_b + (size_t)l * D,
        x, ca_add + (size_t)l * B * D,
        ln1_g + (size_t)l * D, ln1_b + (size_t)l * D,
        ln2_g + (size_t)l * D, ln2_b + (size_t)l * D,
        x, xb, D);
    // FFN1: relu(x@w1^T+b1) -> ffn1b bf16 [M,1024]
    k_gemm_mfma<1, 1><<<dim3(8, M / 128), 256, 0, stream>>>(
        xb, w_f1 + (size_t)l * 1024 * D, ffn_b1 + (size_t)l * 4 * D, ffn1b,
        M, 1024, D);
    // FFN2 + LN3 fused -> x fp32, xb bf16
    k_gemm_ln<1><<<dim3(M / 64), 256, 0, stream>>>(
        ffn1b, w_f2 + (size_t)l * D * 1024, ffn_b2 + (size_t)l * D,
        x, nullptr,
        ln3_g + (size_t)l * D, ln3_b + (size_t)l * D,
        nullptr, nullptr,
        x, xb, 1024);
  }
  // final vocab projection: [M,256]@[10000,256]^T -> out fp32
  k_gemm_mfma<0, 0><<<dim3(79, M / 128), 256, 0, stream>>>(
      xb, w_v, out_b, out, M, 10000, D);
}

// Round 4
// 816.251 us; speedup vs baseline: 2.2776x; 1.0749x over previous
//
#include <hip/hip_runtime.h>
#include <math.h>

constexpr int B = 16, S = 1024, D = 256, E = 64, H = 8, HD = 32;

typedef __attribute__((ext_vector_type(8))) short bf16x8;
typedef __attribute__((ext_vector_type(4))) short bf16x4;
typedef __attribute__((ext_vector_type(4))) float f32x4;

__device__ __forceinline__ float gelu_f(float x) {
  return 0.5f * x * (1.0f + erff(x * 0.70710678118654752440f));
}

__device__ __forceinline__ unsigned short f2bf(float f) {
  union { float f; unsigned u; } x; x.f = f;
  unsigned r = x.u + 0x7fff + ((x.u >> 16) & 1);
  return (unsigned short)(r >> 16);
}

// packed f32x2 -> bf16x2 (RNE), low half = a, high half = b
__device__ __forceinline__ unsigned cvt_pk_bf16(float a, float b) {
  unsigned r;
  asm("v_cvt_pk_bf16_f32 %0, %1, %2" : "=v"(r) : "v"(a), "v"(b));
  return r;
}

// async global->LDS, 16B per lane; lds must be wave-uniform-base + lane*16
__device__ __forceinline__ void gl16(const void* g, void* l) {
  __builtin_amdgcn_global_load_lds(
      (const __attribute__((address_space(1))) void*)g,
      (__attribute__((address_space(3))) void*)l, 16, 0, 0);
}

// ---------------- fp32 -> bf16 conversion (weights) ----------------
__global__ void k_cvt(const float* __restrict__ src, unsigned short* __restrict__ dst, int n) {
  int i = (blockIdx.x * 256 + threadIdx.x) * 4;
  if (i >= n) return;
  float4 v = *(const float4*)(src + i);
  dst[i + 0] = f2bf(v.x);
  dst[i + 1] = f2bf(v.y);
  dst[i + 2] = f2bf(v.z);
  dst[i + 3] = f2bf(v.w);
}

// ---------------- embedding: x = tok_emb[tok] + pos_emb[s] (fp32 + bf16) ----------------
__global__ void k_embed(const int* __restrict__ tok,
                        const float* __restrict__ tok_emb,
                        const float* __restrict__ pos_emb,
                        float* __restrict__ x, unsigned short* __restrict__ xb) {
  int bs = blockIdx.x;
  int d = threadIdx.x;
  int s = bs & (S - 1);
  int t = tok[bs];
  float v = tok_emb[(size_t)t * D + d] + pos_emb[s * D + d];
  x[(size_t)bs * D + d] = v;
  xb[(size_t)bs * D + d] = f2bf(v);
}

// ---------------- encoder branch ----------------
__global__ void k_enc(const float* __restrict__ tr, const float* __restrict__ ctx,
                      const float* __restrict__ card,
                      const float* __restrict__ w, const float* __restrict__ bias,
                      const float* __restrict__ g, const float* __restrict__ bt,
                      float* __restrict__ cat) {
  int b = blockIdx.x, i = blockIdx.y, d = threadIdx.x;
  const float* xin = (i == 0 ? tr : (i == 1 ? ctx : card)) + b * E;
  const float* wr = w + ((size_t)i * D + d) * E;
  float acc = bias[i * D + d];
#pragma unroll 8
  for (int e = 0; e < E; ++e) acc += xin[e] * wr[e];
  __shared__ float s1[D], s2[D];
  s1[d] = acc; s2[d] = acc * acc;
  __syncthreads();
  for (int o = D / 2; o > 0; o >>= 1) {
    if (d < o) { s1[d] += s1[d + o]; s2[d] += s2[d + o]; }
    __syncthreads();
  }
  float mean = s1[0] * (1.0f / D);
  float var = s2[0] * (1.0f / D) - mean * mean;
  float nv = (acc - mean) * rsqrtf(var + 1e-5f) * g[i * D + d] + bt[i * D + d];
  cat[(size_t)b * (3 * D) + i * D + d] = gelu_f(nv);
}

// ---------------- fusion ----------------
__global__ void k_fusion(const float* __restrict__ cat, const float* __restrict__ w,
                         const float* __restrict__ bias, const float* __restrict__ g,
                         const float* __restrict__ bt, float* __restrict__ mem) {
  int b = blockIdx.x, d = threadIdx.x;
  const float* xr = cat + (size_t)b * (3 * D);
  const float* wr = w + (size_t)d * (3 * D);
  float acc = bias[d];
  for (int k = 0; k < 3 * D; ++k) acc += xr[k] * wr[k];
  __shared__ float s1[D], s2[D];
  s1[d] = acc; s2[d] = acc * acc;
  __syncthreads();
  for (int o = D / 2; o > 0; o >>= 1) {
    if (d < o) { s1[d] += s1[d + o]; s2[d] += s2[d + o]; }
    __syncthreads();
  }
  float mean = s1[0] * (1.0f / D);
  float var = s2[0] * (1.0f / D) - mean * mean;
  float nv = (acc - mean) * rsqrtf(var + 1e-5f) * g[d] + bt[d];
  mem[(size_t)b * D + d] = gelu_f(nv);
}

// ---------------- cross-attn collapsed (softmax over 1 key == identity) ----------------
__global__ void k_ca(const float* __restrict__ mem,
                     const float* __restrict__ in_w, const float* __restrict__ in_b,
                     const float* __restrict__ out_w, const float* __restrict__ out_b,
                     float* __restrict__ ca_add) {
  int b = blockIdx.x, l = blockIdx.y, d = threadIdx.x;
  const float* mr = mem + (size_t)b * D;
  const float* wi = in_w + ((size_t)l * 3 * D + 2 * D + d) * D;
  float v = in_b[(size_t)l * 3 * D + 2 * D + d];
  for (int k = 0; k < D; ++k) v += mr[k] * wi[k];
  __shared__ float vs[D];
  vs[d] = v;
  __syncthreads();
  const float* wo = out_w + ((size_t)l * D + d) * D;
  float o = out_b[(size_t)l * D + d];
  for (int k = 0; k < D; ++k) o += vs[k] * wo[k];
  ca_add[((size_t)l * B + b) * D + d] = o;
}

// ---------------- causal flash attention via MFMA, swapped-QK^T softmax ----------------
// 8 waves x 32 queries = 256 queries per block for one (b,h). KT=64 keys/step.
// K/V staged ONCE per block per step (vs twice at 128-q blocks); defer-max (T13).
// QK^T computed as mfma(K,Q): C col=lane&15 = q, row=(lane>>4)*4+reg = k.
__global__ __launch_bounds__(512)
void k_attn6(const unsigned short* __restrict__ qkv, unsigned short* __restrict__ out) {
  constexpr int KT = 64;
  __shared__ unsigned short Ks[2][KT * 32];   // [key][32] linear (gl16 dest)
  __shared__ unsigned short Vt[2][32 * KT];   // [d][key], XOR-swizzled rows
  __shared__ unsigned short Pl[8 * 32 * KT];  // per-wave P [q][k], XOR-swizzled

  const int t = threadIdx.x;
  const int w = t >> 6, lane = t & 63;
  const int lg = lane >> 4, lr = lane & 15;
  const int bh = blockIdx.y;
  const int h = bh & (H - 1), b = bh >> 3;
  const int qtile = (int)gridDim.x - 1 - (int)blockIdx.x;  // biggest tiles first
  const int qb = qtile << 8;    // 256 queries per block
  const int qw = qb + w * 32;   // wave query base
  const unsigned short* base = qkv + (size_t)b * S * 768 + h * HD;

  // Q fragments: lane holds q-row qw + qr*16 + lr, k-chunk lg*8 (HD=32 == MFMA K)
  bf16x8 qf[2];
#pragma unroll
  for (int qr = 0; qr < 2; ++qr)
    qf[qr] = *(const bf16x8*)(base + (size_t)(qw + qr * 16 + lr) * 768 + lg * 8);

  f32x4 o[2][2];  // [qr][dt]; C-layout: col d = dt*16+lr, row q = qr*16+lg*4+r
#pragma unroll
  for (int qr = 0; qr < 2; ++qr)
#pragma unroll
    for (int dt = 0; dt < 2; ++dt) o[qr][dt] = (f32x4){0.f, 0.f, 0.f, 0.f};
  float mq[2], lq[2];  // running max / LANE-LOCAL partial sum for q = qw+qr*16+lr
#pragma unroll
  for (int qr = 0; qr < 2; ++qr) { mq[qr] = -3.0e38f; lq[qr] = 0.f; }

  const float Cs = 0.17677669529663687f * 1.4426950408889634f;  // 1/sqrt(32)*log2(e)

  // K staging (threads 0..255): thread -> key t>>2, 8-elem chunk (t&3)*8
  const int skey = t >> 2;
  const int sch = (t & 3) * 8;
  // V staging (all 512): thread -> key t>>3, 4-elem chunk (t&7)*4
  const int vkey = t >> 3;
  const int vch = (t & 7) * 4;
  char* pbase = (char*)Pl + (w << 12);

  const int nkt = (qb + 256) >> 6;  // 4,8,12,16

  // prologue: stage step 0
  if (t < 256) gl16(base + (size_t)skey * 768 + 256 + sch, (char*)Ks[0] + t * 16);
  bf16x4 vv = *(const bf16x4*)(base + (size_t)vkey * 768 + 512 + vch);
  __syncthreads();  // K0 resident (vmcnt drained), vv loaded

  for (int kti = 0; kti < nkt; ++kti) {
    const int kt = kti << 6;
    const int cur = kti & 1;

    // write current V tile (regs -> LDS transposed, swizzle byte ^= (d&7)<<4)
#pragma unroll
    for (int j = 0; j < 4; ++j) {
      int d = vch + j;
      int byteo = d * (KT * 2) + ((vkey * 2) ^ ((d & 7) << 4));
      *(unsigned short*)((char*)Vt[cur] + byteo) = (unsigned short)vv[j];
    }
    // prefetch next step's K (gl16) and V (regs) — latency hides under QK^T+softmax
    if (kti + 1 < nkt) {
      if (t < 256)
        gl16(base + (size_t)(kt + KT + skey) * 768 + 256 + sch, (char*)Ks[cur ^ 1] + t * 16);
      vv = *(const bf16x4*)(base + (size_t)(kt + KT + vkey) * 768 + 512 + vch);
    }

    const bool active = (kt <= qw + 31);
    if (active) {
      // ---- QK^T (swapped): sc[qr][t4] = mfma(K-tile, Q-tile) ----
      bf16x8 kf[4];
#pragma unroll
      for (int t4 = 0; t4 < 4; ++t4)
        kf[t4] = *(const bf16x8*)&Ks[cur][(t4 * 16 + lr) * 32 + lg * 8];
      f32x4 sc[2][4];
      __builtin_amdgcn_s_setprio(1);
#pragma unroll
      for (int qr = 0; qr < 2; ++qr)
#pragma unroll
        for (int t4 = 0; t4 < 4; ++t4)
          sc[qr][t4] = __builtin_amdgcn_mfma_f32_16x16x32_bf16(
              kf[t4], qf[qr], (f32x4){0.f, 0.f, 0.f, 0.f}, 0, 0, 0);
      __builtin_amdgcn_s_setprio(0);

      // ---- causal mask (diagonal tiles only): k = kt+t4*16+lg*4+r, q = qw+qr*16+lr
      if (kt + KT > qw) {
#pragma unroll
        for (int qr = 0; qr < 2; ++qr) {
          int q = qw + qr * 16 + lr;
#pragma unroll
          for (int t4 = 0; t4 < 4; ++t4)
#pragma unroll
            for (int r = 0; r < 4; ++r) {
              int k = kt + t4 * 16 + lg * 4 + r;
              if (k > q) sc[qr][t4][r] = -3.0e38f;
            }
        }
      }

      // ---- online softmax with defer-max (T13, THR=8) ----
#pragma unroll
      for (int qr = 0; qr < 2; ++qr) {
        // lane-local max over this lane's 16 k-values
        float mx = sc[qr][0][0];
#pragma unroll
        for (int t4 = 0; t4 < 4; ++t4)
#pragma unroll
          for (int r = 0; r < 4; ++r) mx = fmaxf(mx, sc[qr][t4][r]);
        mx = fmaxf(mx, __shfl_xor(mx, 16));
        mx = fmaxf(mx, __shfl_xor(mx, 32));  // full row max of this tile
        // rescale only if some row's max grew past THR (first tile always does)
        if (__any(mx > mq[qr] + 8.0f)) {
          float mn = fmaxf(mx, mq[qr]);
          float cf = exp2f((mq[qr] - mn) * Cs);
          mq[qr] = mn;
          lq[qr] *= cf;
#pragma unroll
          for (int r = 0; r < 4; ++r) {
            float cfo = __shfl(cf, (lane & 48) | (lg * 4 + r));
            o[qr][0][r] *= cfo;
            o[qr][1][r] *= cfo;
          }
        }
        float nmxC = -mq[qr] * Cs;
        float ps = 0.f;
#pragma unroll
        for (int t4 = 0; t4 < 4; ++t4)
#pragma unroll
          for (int r = 0; r < 4; ++r) {
            float p = exp2f(fmaf(sc[qr][t4][r], Cs, nmxC));
            sc[qr][t4][r] = p;
            ps += p;
          }
        lq[qr] += ps;  // lane-local partial (this lg's k subset)
        // ---- P -> wave-local LDS: per t4, 4 contiguous k -> 1 ds_write_b64 ----
        int ql = qr * 16 + lr;
        int swz = (ql & 7) << 4;
        char* prow = pbase + ql * (KT * 2);
#pragma unroll
        for (int t4 = 0; t4 < 4; ++t4) {
          unsigned lo = cvt_pk_bf16(sc[qr][t4][0], sc[qr][t4][1]);
          unsigned hi = cvt_pk_bf16(sc[qr][t4][2], sc[qr][t4][3]);
          *(uint2*)(prow + ((t4 * 32 + lg * 8) ^ swz)) = make_uint2(lo, hi);
        }
      }
    }

    // single barrier: Vt[cur]+P writes visible; next K gl16 drained; vv loaded
    __syncthreads();

    if (active) {
      // ---- PV: 8 MFMAs over 2 key-passes of 32 ----
#pragma unroll
      for (int kp = 0; kp < 2; ++kp) {
        bf16x8 vf[2], pf[2];
        int kb = kp * 64 + lg * 16;  // byte offset of 16B key-chunk
#pragma unroll
        for (int dt = 0; dt < 2; ++dt) {
          int d = dt * 16 + lr;
          vf[dt] = *(const bf16x8*)((char*)Vt[cur] + d * (KT * 2) + (kb ^ ((d & 7) << 4)));
        }
#pragma unroll
        for (int qr = 0; qr < 2; ++qr) {
          int ql = qr * 16 + lr;
          pf[qr] = *(const bf16x8*)(pbase + ql * (KT * 2) + (kb ^ ((ql & 7) << 4)));
        }
        __builtin_amdgcn_s_setprio(1);
#pragma unroll
        for (int qr = 0; qr < 2; ++qr)
#pragma unroll
          for (int dt = 0; dt < 2; ++dt)
            o[qr][dt] = __builtin_amdgcn_mfma_f32_16x16x32_bf16(
                pf[qr], vf[dt], o[qr][dt], 0, 0, 0);
        __builtin_amdgcn_s_setprio(0);
      }
    }
  }

  // ---- epilogue: total l per q (reduce lg-groups), broadcast to o-layout ----
#pragma unroll
  for (int qr = 0; qr < 2; ++qr) {
    float ls = lq[qr];
    ls += __shfl_xor(ls, 16);
    ls += __shfl_xor(ls, 32);
    float invq = 1.0f / ls;  // for q = qw + qr*16 + lr
#pragma unroll
    for (int r = 0; r < 4; ++r) {
      float inv = __shfl(invq, (lane & 48) | (lg * 4 + r));
      int q = qw + qr * 16 + lg * 4 + r;
      unsigned short* orow = out + (size_t)(b * S + q) * D + h * HD;
#pragma unroll
      for (int dt = 0; dt < 2; ++dt)
        orow[dt * 16 + lr] = f2bf(o[qr][dt][r] * inv);
    }
  }
}

// ---------------- bf16 MFMA GEMM: C[M,N] = A[M,K] @ W[N,K]^T + bias ----------------
// 128x128 tile, BK=32, 4 waves each computing 64x64 via 4x4 frags of 16x16x32.
// EPI: 0=none 1=relu. OUTBF: 0=fp32 out, 1=bf16 out.
template <int EPI, int OUTBF>
__global__ __launch_bounds__(256)
void k_gemm_mfma(const unsigned short* __restrict__ A,
                 const unsigned short* __restrict__ W,
                 const float* __restrict__ bias,
                 void* __restrict__ Cout,
                 int M, int N, int K) {
  __shared__ unsigned short As[128][32];
  __shared__ unsigned short Bs[128][32];
  int t = threadIdx.x;
  int row0 = blockIdx.y * 128, col0 = blockIdx.x * 128;
  int wid = t >> 6, lane = t & 63;
  int wr = wid >> 1, wc = wid & 1;
  int lrow = lane & 15, lko = (lane >> 4) * 8;

  f32x4 acc[4][4];
#pragma unroll
  for (int mi = 0; mi < 4; ++mi)
#pragma unroll
    for (int ni = 0; ni < 4; ++ni)
      acc[mi][ni] = (f32x4){0.f, 0.f, 0.f, 0.f};

  int c0 = t, c1 = t + 256;
  int ar0 = c0 >> 2, aq0 = (c0 & 3) * 8;
  int ar1 = c1 >> 2, aq1 = (c1 & 3) * 8;
  int wrow0 = col0 + ar0; if (wrow0 > N - 1) wrow0 = N - 1;
  int wrow1 = col0 + ar1; if (wrow1 > N - 1) wrow1 = N - 1;

  const unsigned short* A0 = A + (size_t)(row0 + ar0) * K + aq0;
  const unsigned short* A1 = A + (size_t)(row0 + ar1) * K + aq1;
  const unsigned short* W0 = W + (size_t)wrow0 * K + aq0;
  const unsigned short* W1 = W + (size_t)wrow1 * K + aq1;

  for (int kt = 0; kt < K; kt += 32) {
    gl16(A0 + kt, (char*)As + c0 * 16);
    gl16(A1 + kt, (char*)As + c1 * 16);
    gl16(W0 + kt, (char*)Bs + c0 * 16);
    gl16(W1 + kt, (char*)Bs + c1 * 16);
    __syncthreads();

    bf16x8 af[4], bfr[4];
#pragma unroll
    for (int mi = 0; mi < 4; ++mi)
      af[mi] = *(const bf16x8*)&As[wr * 64 + mi * 16 + lrow][lko];
#pragma unroll
    for (int ni = 0; ni < 4; ++ni)
      bfr[ni] = *(const bf16x8*)&Bs[wc * 64 + ni * 16 + lrow][lko];
#pragma unroll
    for (int mi = 0; mi < 4; ++mi)
#pragma unroll
      for (int ni = 0; ni < 4; ++ni)
        acc[mi][ni] = __builtin_amdgcn_mfma_f32_16x16x32_bf16(af[mi], bfr[ni], acc[mi][ni], 0, 0, 0);
    __syncthreads();
  }

  int rbase = row0 + wr * 64 + (lane >> 4) * 4;
  int cbase = col0 + wc * 64 + lrow;
#pragma unroll
  for (int ni = 0; ni < 4; ++ni) {
    int c = cbase + ni * 16;
    if (c < N) {
      float bv = bias[c];
#pragma unroll
      for (int mi = 0; mi < 4; ++mi) {
        int rr = rbase + mi * 16;
#pragma unroll
        for (int r = 0; r < 4; ++r) {
          float v = acc[mi][ni][r] + bv;
          if (EPI == 1) v = fmaxf(v, 0.0f);
          size_t off = (size_t)(rr + r) * N + c;
          if (OUTBF)
            ((unsigned short*)Cout)[off] = f2bf(v);
          else
            ((float*)Cout)[off] = v;
        }
      }
    }
  }
}

// ---------------- fused GEMM (N=256) + residual + 1 or 2 LayerNorms ----------------
// Tile 64 rows x 256 cols (full row), 4 waves, BK=32, double-buffered LDS
// (grid = M/64 = 256 blocks = 1/CU -> needs in-block pipelining).
// NLN==1: x = LN(res + A@W^T + bias; g1,b1)
// NLN==2: x1 = LN1(res + A@W^T + bias); x = LN2(x1 + ca[row/S]; g2,b2)
template <int NLN>
__global__ __launch_bounds__(256)
void k_gemm_ln(const unsigned short* __restrict__ A,
               const unsigned short* __restrict__ W,
               const float* __restrict__ bias,
               const float* __restrict__ res,
               const float* __restrict__ ca,
               const float* __restrict__ g1, const float* __restrict__ b1,
               const float* __restrict__ g2, const float* __restrict__ b2,
               float* __restrict__ xout, unsigned short* __restrict__ xb,
               int K) {
  __shared__ unsigned short As[2][64][32];
  __shared__ unsigned short Bs[2][256][32];
  __shared__ float red[2][64][4];
  int t = threadIdx.x;
  int row0 = blockIdx.x * 64;
  int wc = t >> 6, lane = t & 63;
  int lr = lane & 15, lg = lane >> 4;

  f32x4 acc[4][4];  // [mi rows][ni cols]
#pragma unroll
  for (int mi = 0; mi < 4; ++mi)
#pragma unroll
    for (int ni = 0; ni < 4; ++ni)
      acc[mi][ni] = (f32x4){0.f, 0.f, 0.f, 0.f};

  // staging: 1280 16B-chunks (As 256 + Bs 1024), 5 per thread, per buffer
  const unsigned short* srcs[5];
  char* dsts[2][5];
#pragma unroll
  for (int i = 0; i < 5; ++i) {
    int c = t + (i << 8);
    if (c < 256) {
      int rw = c >> 2, q = (c & 3) * 8;
      srcs[i] = A + (size_t)(row0 + rw) * K + q;
      dsts[0][i] = (char*)As[0] + c * 16;
      dsts[1][i] = (char*)As[1] + c * 16;
    } else {
      int cb = c - 256;
      int rw = cb >> 2, q = (cb & 3) * 8;
      srcs[i] = W + (size_t)rw * K + q;
      dsts[0][i] = (char*)Bs[0] + cb * 16;
      dsts[1][i] = (char*)Bs[1] + cb * 16;
    }
  }

  const int nsteps = K >> 5;
  // prologue: stage step 0
#pragma unroll
  for (int i = 0; i < 5; ++i) gl16(srcs[i], dsts[0][i]);
  __syncthreads();

  for (int s = 0; s < nsteps; ++s) {
    const int cur = s & 1;
    // prefetch next step into the other buffer (drained by the end barrier)
    if (s + 1 < nsteps) {
      int off = (s + 1) << 5;
#pragma unroll
      for (int i = 0; i < 5; ++i) gl16(srcs[i] + off, dsts[cur ^ 1][i]);
    }
    bf16x8 af[4], bfr[4];
#pragma unroll
    for (int mi = 0; mi < 4; ++mi)
      af[mi] = *(const bf16x8*)&As[cur][mi * 16 + lr][lg * 8];
#pragma unroll
    for (int ni = 0; ni < 4; ++ni)
      bfr[ni] = *(const bf16x8*)&Bs[cur][wc * 64 + ni * 16 + lr][lg * 8];
    __builtin_amdgcn_s_setprio(1);
#pragma unroll
    for (int mi = 0; mi < 4; ++mi)
#pragma unroll
      for (int ni = 0; ni < 4; ++ni)
        acc[mi][ni] = __builtin_amdgcn_mfma_f32_16x16x32_bf16(af[mi], bfr[ni], acc[mi][ni], 0, 0, 0);
    __builtin_amdgcn_s_setprio(0);
    __syncthreads();  // next-tile gl16 drained; cur reads consumed
  }

  // ---- epilogue: v = acc + bias + res; LN over the full 256-col row ----
  int colb = wc * 64 + lr;
  float mean[4][4], rstd[4][4];

#pragma unroll
  for (int mi = 0; mi < 4; ++mi) {
#pragma unroll
    for (int r = 0; r < 4; ++r) {
      int rowl = mi * 16 + lg * 4 + r;
      int rowg = row0 + rowl;
      float s1 = 0.f, s2 = 0.f;
#pragma unroll
      for (int ni = 0; ni < 4; ++ni) {
        int c = colb + ni * 16;
        float v = acc[mi][ni][r] + bias[c] + res[(size_t)rowg * D + c];
        acc[mi][ni][r] = v;
        s1 += v; s2 += v * v;
      }
#pragma unroll
      for (int msk = 1; msk <= 8; msk <<= 1) {
        s1 += __shfl_xor(s1, msk);
        s2 += __shfl_xor(s2, msk);
      }
      if (lr == 0) { red[0][rowl][wc] = s1; red[1][rowl][wc] = s2; }
    }
  }
  __syncthreads();
#pragma unroll
  for (int mi = 0; mi < 4; ++mi)
#pragma unroll
    for (int r = 0; r < 4; ++r) {
      int rowl = mi * 16 + lg * 4 + r;
      f32x4 a = *(const f32x4*)&red[0][rowl][0];
      f32x4 bq = *(const f32x4*)&red[1][rowl][0];
      float s1 = a[0] + a[1] + a[2] + a[3];
      float s2 = bq[0] + bq[1] + bq[2] + bq[3];
      float mn = s1 * (1.0f / D);
      float vr = s2 * (1.0f / D) - mn * mn;
      mean[mi][r] = mn;
      rstd[mi][r] = rsqrtf(vr + 1e-5f);
    }
#pragma unroll
  for (int mi = 0; mi < 4; ++mi)
#pragma unroll
    for (int ni = 0; ni < 4; ++ni) {
      int c = colb + ni * 16;
      float gg = g1[c], bb = b1[c];
#pragma unroll
      for (int r = 0; r < 4; ++r)
        acc[mi][ni][r] = (acc[mi][ni][r] - mean[mi][r]) * rstd[mi][r] * gg + bb;
    }

  if (NLN == 2) {
    __syncthreads();  // red reads done; safe to rewrite
#pragma unroll
    for (int mi = 0; mi < 4; ++mi) {
#pragma unroll
      for (int r = 0; r < 4; ++r) {
        int rowl = mi * 16 + lg * 4 + r;
        int rowg = row0 + rowl;
        int bidx = rowg >> 10;  // row / S
        float s1 = 0.f, s2 = 0.f;
#pragma unroll
        for (int ni = 0; ni < 4; ++ni) {
          int c = colb + ni * 16;
          float v = acc[mi][ni][r] + ca[(size_t)bidx * D + c];
          acc[mi][ni][r] = v;
          s1 += v; s2 += v * v;
        }
#pragma unroll
        for (int msk = 1; msk <= 8; msk <<= 1) {
          s1 += __shfl_xor(s1, msk);
          s2 += __shfl_xor(s2, msk);
        }
        if (lr == 0) { red[0][rowl][wc] = s1; red[1][rowl][wc] = s2; }
      }
    }
    __syncthreads();
#pragma unroll
    for (int mi = 0; mi < 4; ++mi)
#pragma unroll
      for (int r = 0; r < 4; ++r) {
        int rowl = mi * 16 + lg * 4 + r;
        f32x4 a = *(const f32x4*)&red[0][rowl][0];
        f32x4 bq = *(const f32x4*)&red[1][rowl][0];
        float s1 = a[0] + a[1] + a[2] + a[3];
        float s2 = bq[0] + bq[1] + bq[2] + bq[3];
        float mn = s1 * (1.0f / D);
        float vr = s2 * (1.0f / D) - mn * mn;
        mean[mi][r] = mn;
        rstd[mi][r] = rsqrtf(vr + 1e-5f);
      }
#pragma unroll
    for (int mi = 0; mi < 4; ++mi)
#pragma unroll
      for (int ni = 0; ni < 4; ++ni) {
        int c = colb + ni * 16;
        float gg = g2[c], bb = b2[c];
#pragma unroll
        for (int r = 0; r < 4; ++r)
          acc[mi][ni][r] = (acc[mi][ni][r] - mean[mi][r]) * rstd[mi][r] * gg + bb;
      }
  }

  // write x fp32 + bf16 shadow
#pragma unroll
  for (int mi = 0; mi < 4; ++mi)
#pragma unroll
    for (int r = 0; r < 4; ++r) {
      int rowg = row0 + mi * 16 + lg * 4 + r;
#pragma unroll
      for (int ni = 0; ni < 4; ++ni) {
        int c = colb + ni * 16;
        float v = acc[mi][ni][r];
        xout[(size_t)rowg * D + c] = v;
        xb[(size_t)rowg * D + c] = f2bf(v);
      }
    }
}

extern "C" void kernel_launch(void* const* d_in, const int* in_sizes, int n_in,
                              void* d_out, int out_size, void* d_ws, size_t ws_size,
                              hipStream_t stream) {
  (void)in_sizes; (void)n_in; (void)out_size; (void)ws_size;
  const float* tractovka = (const float*)d_in[0];
  const float* context   = (const float*)d_in[1];
  const float* card      = (const float*)d_in[2];
  const float* enc_w     = (const float*)d_in[3];
  const float* enc_b     = (const float*)d_in[4];
  const float* enc_ln_g  = (const float*)d_in[5];
  const float* enc_ln_b  = (const float*)d_in[6];
  const float* fusion_w  = (const float*)d_in[7];
  const float* fusion_b  = (const float*)d_in[8];
  const float* fusion_ln_g = (const float*)d_in[9];
  const float* fusion_ln_b = (const float*)d_in[10];
  const float* tok_emb   = (const float*)d_in[11];
  const float* pos_emb   = (const float*)d_in[12];
  const float* sa_in_w   = (const float*)d_in[13];
  const float* sa_in_b   = (const float*)d_in[14];
  const float* sa_out_w  = (const float*)d_in[15];
  const float* sa_out_b  = (const float*)d_in[16];
  const float* ca_in_w   = (const float*)d_in[17];
  const float* ca_in_b   = (const float*)d_in[18];
  const float* ca_out_w  = (const float*)d_in[19];
  const float* ca_out_b  = (const float*)d_in[20];
  const float* ln1_g     = (const float*)d_in[21];
  const float* ln1_b     = (const float*)d_in[22];
  const float* ln2_g     = (const float*)d_in[23];
  const float* ln2_b     = (const float*)d_in[24];
  const float* ln3_g     = (const float*)d_in[25];
  const float* ln3_b     = (const float*)d_in[26];
  const float* ffn_w1    = (const float*)d_in[27];
  const float* ffn_b1    = (const float*)d_in[28];
  const float* ffn_w2    = (const float*)d_in[29];
  const float* ffn_b2    = (const float*)d_in[30];
  const float* out_w     = (const float*)d_in[31];
  const float* out_b     = (const float*)d_in[32];
  const int*   prev      = (const int*)d_in[33];
  float* out = (float*)d_out;

  const int M = B * S;  // 16384

  float* ws = (float*)d_ws;
  float* x      = ws;                        // M*D f32
  float* bufA   = x + (size_t)M * D;         // M*768 region (QKV bf16; aliased by ffn1b)
  float* bufB   = bufA + (size_t)M * 768;    // M*D f32 (unused now, kept for layout)
  float* cat    = bufB + (size_t)M * D;      // B*3D
  float* mem    = cat + (size_t)B * 3 * D;   // B*D
  float* ca_add = mem + (size_t)B * D;       // 3*B*D
  unsigned short* xb    = (unsigned short*)(ca_add + (size_t)3 * B * D);  // M*D bf16
  unsigned short* attnb = xb + (size_t)M * D;                             // M*D bf16
  unsigned short* wbf   = attnb + (size_t)M * D;                          // weights bf16
  unsigned short* qkvb  = (unsigned short*)bufA;                          // M*768 bf16 (alias)
  unsigned short* ffn1b = (unsigned short*)bufA;                          // M*1024 bf16 (alias)

  const int n_qkvw = 3 * 768 * D;    // 589824
  const int n_outw = 3 * D * D;      // 196608
  const int n_f1w  = 3 * 1024 * D;   // 786432
  const int n_f2w  = 3 * D * 1024;   // 786432
  const int n_vw   = 10000 * D;      // 2560000
  unsigned short* w_qkv = wbf;
  unsigned short* w_out = w_qkv + n_qkvw;
  unsigned short* w_f1  = w_out + n_outw;
  unsigned short* w_f2  = w_f1 + n_f1w;
  unsigned short* w_v   = w_f2 + n_f2w;

  // weight conversions (fp32 -> bf16), ~20 MB total
  k_cvt<<<(n_qkvw / 4 + 255) / 256, 256, 0, stream>>>(sa_in_w, w_qkv, n_qkvw);
  k_cvt<<<(n_outw / 4 + 255) / 256, 256, 0, stream>>>(sa_out_w, w_out, n_outw);
  k_cvt<<<(n_f1w / 4 + 255) / 256, 256, 0, stream>>>(ffn_w1, w_f1, n_f1w);
  k_cvt<<<(n_f2w / 4 + 255) / 256, 256, 0, stream>>>(ffn_w2, w_f2, n_f2w);
  k_cvt<<<(n_vw / 4 + 255) / 256, 256, 0, stream>>>(out_w, w_v, n_vw);

  // embedding (+bf16 shadow)
  k_embed<<<M, D, 0, stream>>>(prev, tok_emb, pos_emb, x, xb);
  // encoder side path
  k_enc<<<dim3(B, 3), D, 0, stream>>>(tractovka, context, card, enc_w, enc_b,
                                      enc_ln_g, enc_ln_b, cat);
  k_fusion<<<B, D, 0, stream>>>(cat, fusion_w, fusion_b, fusion_ln_g, fusion_ln_b, mem);
  k_ca<<<dim3(B, 3), D, 0, stream>>>(mem, ca_in_w, ca_in_b, ca_out_w, ca_out_b, ca_add);

  for (int l = 0; l < 3; ++l) {
    // QKV: [M,256]@[768,256]^T -> qkvb bf16 [M,768]
    k_gemm_mfma<0, 1><<<dim3(6, M / 128), 256, 0, stream>>>(
        xb, w_qkv + (size_t)l * 768 * D, sa_in_b + (size_t)l * 3 * D, qkvb,
        M, 768, D);
    // causal self-attention (MFMA flash, 256q/block, defer-max) -> attnb bf16
    k_attn6<<<dim3(S / 256, B * H), 512, 0, stream>>>(qkvb, attnb);
    // out-proj + LN1 + (+ca_add) + LN2 fused -> x fp32, xb bf16
    k_gemm_ln<2><<<dim3(M / 64), 256, 0, stream>>>(
        attnb, w_out + (size_t)l * D * D, sa_out_b + (size_t)l * D,
        x, ca_add + (size_t)l * B * D,
        ln1_g + (size_t)l * D, ln1_b + (size_t)l * D,
        ln2_g + (size_t)l * D, ln2_b + (size_t)l * D,
        x, xb, D);
    // FFN1: relu(x@w1^T+b1) -> ffn1b bf16 [M,1024]
    k_gemm_mfma<1, 1><<<dim3(8, M / 128), 256, 0, stream>>>(
        xb, w_f1 + (size_t)l * 1024 * D, ffn_b1 + (size_t)l * 4 * D, ffn1b,
        M, 1024, D);
    // FFN2 + LN3 fused -> x fp32, xb bf16
    k_gemm_ln<1><<<dim3(M / 64), 256, 0, stream>>>(
        ffn1b, w_f2 + (size_t)l * D * 1024, ffn_b2 + (size_t)l * D,
        x, nullptr,
        ln3_g + (size_t)l * D, ln3_b + (size_t)l * D,
        nullptr, nullptr,
        x, xb, 1024);
  }
  // final vocab projection: [M,256]@[10000,256]^T -> out fp32
  k_gemm_mfma<0, 0><<<dim3(79, M / 128), 256, 0, stream>>>(
      xb, w_v, out_b, out, M, 10000, D);
}